// Round 10
// baseline (1692.159 us; speedup 1.0000x reference)
//
#include <hip/hip_runtime.h>
#include <cstddef>

#define EPSF 1e-12f

constexpr int Bc = 16, Dc = 128, Lc = 4096, Kc = 4096;
constexpr int Nc = Bc * Lc;     // 65536
constexpr float TAU = 1e-4f;    // 2x split-bf16 err (~4e-5) + 8-bit pack err (~6e-5)
constexpr int RCAP = 32768;

typedef __attribute__((ext_vector_type(8))) short short8;
typedef __attribute__((ext_vector_type(4))) float f32x4;

__device__ __forceinline__ unsigned short f2bf(float f) {
    unsigned u = __float_as_uint(f);
    return (unsigned short)((u + 0x7fffu + ((u >> 16) & 1u)) >> 16);
}
__device__ __forceinline__ float bf2f(unsigned short u) {
    return __uint_as_float(((unsigned)u) << 16);
}

// ---------------------------------------------------------------------------
// Fused codebook prep: normalize -> cbn (f32) AND pack MFMA-operand blob.
// Blob layout: group g (16 codes) -> 8 frags (kd 0..3 x {hi,lo}) of 1024B;
// within a frag, 16B slot l = q*16 + (k&15) holds bf16 of dims (kd*4+q)*8..+7
// of code k. Zero-inits loss / repair / done / tickets (graph-replay safe).
// ---------------------------------------------------------------------------
__global__ void k_prep(const float* __restrict__ emb, float* __restrict__ cbn,
                       char* __restrict__ blob, float* __restrict__ lacc,
                       int* __restrict__ rcnt, int* __restrict__ done,
                       int* __restrict__ tix) {
    __shared__ float cls[4][128];
    const int tid  = threadIdx.x;
    const int w    = tid >> 6;
    const int lane = tid & 63;
    const int k    = (blockIdx.x << 2) + w;

    float2 v = ((const float2*)(emb + (size_t)k * Dc))[lane];
    float s = v.x * v.x + v.y * v.y;
    #pragma unroll
    for (int off = 32; off > 0; off >>= 1) s += __shfl_down(s, off);
    s = __shfl(s, 0);
    float inv = 1.f / fmaxf(sqrtf(s), EPSF);
    v.x *= inv; v.y *= inv;
    ((float2*)(cbn + (size_t)k * Dc))[lane] = v;
    cls[w][lane * 2]     = v.x;
    cls[w][lane * 2 + 1] = v.y;
    if (blockIdx.x == 0 && tid == 0) { *lacc = 0.f; *rcnt = 0; *done = 0; }
    if (blockIdx.x == 0) tix[tid] = 0;   // 256 tickets, 256 threads
    __syncthreads();

    if (tid < 64) {           // 4 codes x 16 chunks
        int kl = tid >> 4, c = tid & 15;
        int kk = (blockIdx.x << 2) + kl;
        int kd = c >> 2, q = c & 3;
        short8 hh, ll;
        #pragma unroll
        for (int j = 0; j < 8; ++j) {
            float f = cls[kl][c * 8 + j];
            unsigned short hb = f2bf(f);
            hh[j] = (short)hb;
            ll[j] = (short)f2bf(f - bf2f(hb));
        }
        size_t base = (size_t)(kk >> 4) * 8192 + (size_t)(q * 16 + (kk & 15)) * 16;
        *(short8*)(blob + base + (kd * 2 + 0) * 1024) = hh;
        *(short8*)(blob + base + (kd * 2 + 1) * 1024) = ll;
    }
}

// ---------------------------------------------------------------------------
// MFMA argmax, split-K. Blocks (b, b+256) process the SAME 256 rows, each
// over half the codebook (64 tiles). Per-wave register shape IDENTICAL to
// the proven r9 loop (128 VGPR) -> launch_bounds(512,4) fits 2 blocks/CU =
// 4 waves/SIMD: one wave's MFMA burst overlaps another's fold burst (TLP).
// Cross-half merge: both halves publish per-row (packed v1|k1, v2) via
// DEVICE-SCOPE atomics (cross-XCD safe), threadfence, ticket atomicAdd;
// first finisher exits, second merges exactly and does the gather-write
// tail. No spinning -> no deadlock; degrades gracefully at 1 block/CU.
// ---------------------------------------------------------------------------
__global__ __launch_bounds__(512, 4)
void k_argmax(const float* __restrict__ x, const char* __restrict__ blob,
              const float* __restrict__ cbn, float* __restrict__ invn,
              float* __restrict__ out, float* __restrict__ lossacc,
              int* __restrict__ rcnt, int* __restrict__ rlist,
              unsigned long long* __restrict__ pkey, float* __restrict__ pv2b,
              int* __restrict__ tix) {
    __shared__ __align__(16) char smem[33280];
    float* xt   = (float*)smem;              // [64][129] (preamble overlay)
    float* invl = (float*)(smem + 33024);    // [64]

    const int tid  = threadIdx.x;
    const int w    = tid >> 6;
    const int lane = tid & 63;
    const int m16  = lane & 15;
    const int quad = lane >> 4;
    const int rs   = w >> 1;      // rowset 0..3 (64 rows each)
    const int cs   = w & 1;       // codeset 0/1 (16 codes per tile)
    const int rgid = blockIdx.x & 255;
    const int half = blockIdx.x >> 8;
    const int n0   = rgid * 256;
    const int bI   = n0 >> 12;
    const int l0   = n0 & (Lc - 1);
    const float* xb = x + (size_t)bI * Dc * Lc;

    // ---- preamble: 4 halves of 64 rows: transpose, normalize, build A frags
    short8 ah[4][4], al[4][4];
    for (int h = 0; h < 4; ++h) {
        __syncthreads();
        #pragma unroll
        for (int j = 0; j < 4; ++j) {
            int fl = tid + j * 512;              // 0..2047
            int d = fl >> 4, lq = fl & 15;
            float4 v = *(const float4*)(xb + (size_t)d * Lc + l0 + h * 64 + lq * 4);
            xt[(lq * 4 + 0) * 129 + d] = v.x;
            xt[(lq * 4 + 1) * 129 + d] = v.y;
            xt[(lq * 4 + 2) * 129 + d] = v.z;
            xt[(lq * 4 + 3) * 129 + d] = v.w;
        }
        __syncthreads();
        {   // row norms, 8 threads/row
            int row = tid >> 3, q = tid & 7;
            float s = 0.f;
            #pragma unroll
            for (int j = 0; j < 16; ++j) { float t = xt[row * 129 + q * 16 + j]; s += t * t; }
            s += __shfl_down(s, 1); s += __shfl_down(s, 2); s += __shfl_down(s, 4);
            if (q == 0) {
                float inv = 1.f / fmaxf(sqrtf(s), EPSF);
                invl[row] = inv;
                invn[n0 + h * 64 + row] = inv;   // both halves write same value
            }
        }
        __syncthreads();
        if (rs == h) {
            #pragma unroll
            for (int rt = 0; rt < 4; ++rt) {
                int rl = rt * 16 + m16;          // A layout: m = lane&15
                float inv = invl[rl];
                #pragma unroll
                for (int kd = 0; kd < 4; ++kd) {
                    int dof = kd * 32 + quad * 8;   // k = quad*8 + j
                    short8 hhv, llv;
                    #pragma unroll
                    for (int j = 0; j < 8; ++j) {
                        float xn = xt[rl * 129 + dof + j] * inv;
                        unsigned short hb = f2bf(xn);
                        hhv[j] = (short)hb;
                        llv[j] = (short)f2bf(xn - bf2f(hb));
                    }
                    ah[rt][kd] = hhv; al[rt][kd] = llv;
                }
            }
        }
    }
    __syncthreads();

    // ---- K loop: 64 tiles of 32 codes (16 per codeset), barrier-free ----
    const f32x4 fz = {0.f, 0.f, 0.f, 0.f};
    float Bb[16], Ss[16];
    #pragma unroll
    for (int i = 0; i < 16; ++i) { Bb[i] = -3.0e38f; Ss[i] = -3.0e38f; }
    unsigned kc8 = (unsigned)(half * 128 + cs);   // tag = global group index

    const char* pb = blob + (size_t)half * (1u << 20)
                          + (size_t)cs * 8192 + (size_t)lane * 16;

    auto tileStep = [&](const short8* Bf) {
        f32x4 acc[4];
        __builtin_amdgcn_s_setprio(1);
        #pragma unroll
        for (int kd = 0; kd < 4; ++kd) {
            short8 bh = Bf[kd * 2];
            short8 bl = Bf[kd * 2 + 1];
            #pragma unroll
            for (int rt = 0; rt < 4; ++rt)
                acc[rt] = __builtin_amdgcn_mfma_f32_16x16x32_bf16(
                    ah[rt][kd], bh, (kd == 0) ? fz : acc[rt], 0, 0, 0);
            #pragma unroll
            for (int rt = 0; rt < 4; ++rt)
                acc[rt] = __builtin_amdgcn_mfma_f32_16x16x32_bf16(
                    ah[rt][kd], bl, acc[rt], 0, 0, 0);
            #pragma unroll
            for (int rt = 0; rt < 4; ++rt)
                acc[rt] = __builtin_amdgcn_mfma_f32_16x16x32_bf16(
                    al[rt][kd], bh, acc[rt], 0, 0, 0);
        }
        __builtin_amdgcn_s_setprio(0);
        // fold: Ss <= Bb invariant -> med3(Bb, p, Ss) is exact second-best.
        #pragma unroll
        for (int rt = 0; rt < 4; ++rt)
            #pragma unroll
            for (int rg = 0; rg < 4; ++rg) {
                int s = rt * 4 + rg;
                float p = __uint_as_float(
                    (__float_as_uint(acc[rt][rg]) & 0xFFFFFF00u) | kc8);
                Ss[s] = __builtin_amdgcn_fmed3f(Bb[s], p, Ss[s]);
                Bb[s] = fmaxf(Bb[s], p);
            }
        kc8 += 2;
    };

    short8 bA[8], bB[8];
    #pragma unroll
    for (int f = 0; f < 8; ++f) bA[f] = *(const short8*)(pb + f * 1024);

    for (int tt = 0; tt < 32; ++tt) {
        {   // even tile t = 2*tt: prefetch t+1 into bB, compute bA
            const int t = 2 * tt;
            const char* p = pb + (size_t)(t + 1) * 16384;
            #pragma unroll
            for (int f = 0; f < 8; ++f) bB[f] = *(const short8*)(p + f * 1024);
            tileStep(bA);
        }
        {   // odd tile t = 2*tt+1: prefetch t+1 into bA (clamp last), compute bB
            const int t = 2 * tt + 1;
            const size_t tn = (t < 63) ? (size_t)(t + 1) : (size_t)t;
            const char* p = pb + tn * 16384;
            #pragma unroll
            for (int f = 0; f < 8; ++f) bA[f] = *(const short8*)(p + f * 1024);
            tileStep(bB);
        }
    }

    // ---- epilogue: merge 16 m16-lanes per slot ----
    float mv1[16], mv2[16]; int mk1[16];
    #pragma unroll
    for (int s = 0; s < 16; ++s) {
        float v1 = Bb[s], v2 = Ss[s];
        int k1 = (int)(((__float_as_uint(v1) & 0xFFu) << 4) | (unsigned)m16);
        #pragma unroll
        for (int off = 1; off < 16; off <<= 1) {
            float ov1 = __shfl_xor(v1, off);
            float ov2 = __shfl_xor(v2, off);
            int   ok1 = __shfl_xor(k1, off);
            bool gt = ov1 > v1, eq = ov1 == v1;
            v2 = gt ? fmaxf(ov2, v1) : fmaxf(v2, ov1);
            v1 = gt ? ov1 : v1;
            k1 = gt ? ok1 : (eq ? min(k1, ok1) : k1);
        }
        mv1[s] = v1; mv2[s] = v2; mk1[s] = k1;
    }
    // cross-codeset merge via LDS: [256 rows][2 cs]
    float* Ev = (float*)smem;                // 2048 B
    float* Sv = (float*)(smem + 2048);
    int*   Kv = (int*)(smem + 4096);
    float* bsum = (float*)(smem + 6144);
    int*   sOld = (int*)(smem + 6152);
    int*   sidx = (int*)(smem + 8192);       // [256] final code per row
    __syncthreads();
    if (tid == 0) *bsum = 0.f;
    if (m16 == 0) {
        #pragma unroll
        for (int s = 0; s < 16; ++s) {
            int rt = s >> 2, rg = s & 3;
            int row = rs * 64 + rt * 16 + quad * 4 + rg;   // C row = quad*4+reg
            Ev[row * 2 + cs] = mv1[s];
            Sv[row * 2 + cs] = mv2[s];
            Kv[row * 2 + cs] = mk1[s];
        }
    }
    __syncthreads();

    float v1 = 0.f, v2 = 0.f; int k1 = 0;
    unsigned long long mykey = 0ull;
    if (tid < 256) {
        v1 = Ev[tid * 2]; v2 = Sv[tid * 2]; k1 = Kv[tid * 2];
        float ov1 = Ev[tid * 2 + 1], ov2 = Sv[tid * 2 + 1];
        int   ok1 = Kv[tid * 2 + 1];
        bool gt = ov1 > v1, eq = ov1 == v1;
        v2 = gt ? fmaxf(ov2, v1) : fmaxf(v2, ov1);
        v1 = gt ? ov1 : v1;
        k1 = gt ? ok1 : (eq ? min(k1, ok1) : k1);
        // publish my half's partial (device-scope atomics: cross-XCD safe)
        unsigned kb = __float_as_uint(v1);
        kb = (kb & 0x80000000u) ? ~kb : (kb | 0x80000000u);
        mykey = ((unsigned long long)kb << 32)
              | (unsigned)(0xFFFFFFFFu - (unsigned)k1);
        size_t pi = (size_t)half * Nc + n0 + tid;
        atomicExch(&pkey[pi], mykey);
        atomicExch(&pv2b[pi], v2);
    }
    __threadfence();
    __syncthreads();
    if (tid == 0) *sOld = atomicAdd(&tix[rgid], 1);
    __syncthreads();
    if (*sOld == 0) return;          // first finisher: partials published
    __threadfence();

    if (tid < 256) {                 // winner: merge partner's half exactly
        size_t o = (size_t)(1 - half) * Nc + n0 + tid;
        unsigned long long okey = atomicAdd(&pkey[o], 0ull);
        float ov2 = atomicAdd(&pv2b[o], 0.f);
        unsigned okb = (unsigned)(okey >> 32);
        float ov1 = __uint_as_float((okb & 0x80000000u) ? (okb & 0x7FFFFFFFu)
                                                        : ~okb);
        int ok1 = (int)(0xFFFFFFFFu - (unsigned)(okey & 0xFFFFFFFFull));
        bool take = okey > mykey;    // larger v1, tie -> smaller k1
        float nv2 = take ? fmaxf(ov2, v1) : fmaxf(v2, ov1);
        float nv1 = take ? ov1 : v1;
        int   nk1 = take ? ok1 : k1;
        sidx[tid] = nk1;
        atomicAdd(bsum, nv1);
        if (nv1 - nv2 < TAU) {
            int pos = atomicAdd(rcnt, 1);
            if (pos < RCAP) rlist[pos] = n0 + tid;
        }
    }
    __syncthreads();
    if (tid == 0) atomicAdd(lossacc, *bsum);

    // ---- fused output write via LDS transpose: 4 chunks of 64 rows.
    int myk[4];
    #pragma unroll
    for (int c = 0; c < 4; ++c) myk[c] = sidx[c * 64 + (tid >> 3)];
    float* tb = (float*)smem;                // [64][130] = 33280 B
    float* ob = out + (size_t)bI * Dc * Lc + l0;
    #pragma unroll 1
    for (int c = 0; c < 4; ++c) {
        __syncthreads();
        {
            const float4* src = (const float4*)(cbn + (size_t)myk[c] * Dc + (tid & 7) * 16);
            float4 v0 = src[0], vv1 = src[1], vv2 = src[2], vv3 = src[3];
            float* dst = tb + (tid >> 3) * 130 + (tid & 7) * 16;
            *(float4*)(dst + 0)  = v0;
            *(float4*)(dst + 4)  = vv1;
            *(float4*)(dst + 8)  = vv2;
            *(float4*)(dst + 12) = vv3;
        }
        __syncthreads();
        {
            int l = tid & 63, d0 = tid >> 6;     // wave = fixed d, l 0..63
            #pragma unroll
            for (int dd = 0; dd < 16; ++dd) {
                int d = d0 * 16 + dd;
                ob[(size_t)d * Lc + c * 64 + l] = tb[l * 130 + d];
            }
        }
    }
}

// ---------------------------------------------------------------------------
// Exact fp32 re-argmax for flagged queries; rewrites the output row with the
// exact code. Last block (device-scope done counter) writes the scalar loss.
// ---------------------------------------------------------------------------
__global__ __launch_bounds__(256)
void k_repair(const float* __restrict__ x, const float* __restrict__ invn,
              const float* __restrict__ cbn, float* __restrict__ out,
              const int* __restrict__ rcnt, const int* __restrict__ rlist,
              const float* __restrict__ lacc, int* __restrict__ done) {
    __shared__ float xs[128];
    __shared__ unsigned long long red[4];
    __shared__ int fk;
    int cnt = *rcnt; if (cnt > RCAP) cnt = RCAP;
    const int tid = threadIdx.x;
    for (int e = blockIdx.x; e < cnt; e += gridDim.x) {
        int n = rlist[e]; int b = n >> 12; int l = n & (Lc - 1);
        __syncthreads();
        if (tid < 128)
            xs[tid] = x[(size_t)b * Dc * Lc + (size_t)tid * Lc + l] * invn[n];
        __syncthreads();
        const float4* xv = (const float4*)xs;
        float best = -3.0e38f; int bk = 0;
        #pragma unroll 1
        for (int i = 0; i < 16; ++i) {
            int k = i * 256 + tid;                // ascending: '>' keeps min k
            const float4* cr = (const float4*)(cbn + (size_t)k * Dc);
            float s = 0.f;
            #pragma unroll
            for (int j = 0; j < 32; ++j) {
                float4 c = cr[j], xx = xv[j];
                s = fmaf(c.x, xx.x, s); s = fmaf(c.y, xx.y, s);
                s = fmaf(c.z, xx.z, s); s = fmaf(c.w, xx.w, s);
            }
            if (s > best) { best = s; bk = k; }
        }
        unsigned kb = __float_as_uint(best);
        kb = (kb & 0x80000000u) ? ~kb : (kb | 0x80000000u);
        unsigned long long pk =
            ((unsigned long long)kb << 32) | (unsigned)(0xFFFFFFFFu - (unsigned)bk);
        #pragma unroll
        for (int off = 32; off >= 1; off >>= 1) {
            unsigned long long o = __shfl_xor(pk, off);
            pk = (o > pk) ? o : pk;
        }
        if ((tid & 63) == 0) red[tid >> 6] = pk;
        __syncthreads();
        if (tid == 0) {
            unsigned long long m = red[0];
            for (int i = 1; i < 4; ++i) if (red[i] > m) m = red[i];
            fk = (int)(0xFFFFFFFFu - (unsigned)(m & 0xFFFFFFFFull));
        }
        __syncthreads();
        if (tid < 128)       // rewrite output row with exact code
            out[(size_t)b * Dc * Lc + (size_t)tid * Lc + l] = cbn[(size_t)fk * Dc + tid];
    }
    // ---- fused loss finalize: last block writes the scalar
    __syncthreads();
    if (tid == 0) {
        int old = atomicAdd(done, 1);
        if (old == (int)gridDim.x - 1)
            out[(size_t)Bc * Dc * Lc] = 2.0f - 2.0f * (*lacc) / (float)Nc;
    }
}

// ---------------------------------------------------------------------------
extern "C" void kernel_launch(void* const* d_in, const int* in_sizes, int n_in,
                              void* d_out, int out_size, void* d_ws, size_t ws_size,
                              hipStream_t stream) {
    const float* x   = (const float*)d_in[0];   // [16][128][4096] fp32
    const float* emb = (const float*)d_in[1];   // [4096][128] fp32
    float* out = (float*)d_out;

    char* ws = (char*)d_ws;
    float* cbn  = (float*)ws;                                  // 2 MB
    char*  blob = ws + (2u << 20);                             // 2 MB
    float* invn = (float*)(ws + (4u << 20));                   // 256 KB
    char*  b5   = ws + (4u << 20) + (512u << 10);
    float* lacc = (float*)b5;
    int*   rcnt = (int*)(b5 + 64);
    int*   done = (int*)(b5 + 128);
    int*   tix  = (int*)(b5 + 1024);                           // 1 KB
    int*   rlist= (int*)(b5 + 4096);                           // 128 KB
    unsigned long long* pkey = (unsigned long long*)(ws + (5u << 20)); // 1 MB
    float* pv2b = (float*)(ws + (6u << 20));                   // 512 KB

    k_prep  <<<Kc / 4,   256, 0, stream>>>(emb, cbn, blob, lacc, rcnt, done, tix);
    k_argmax<<<2 * Nc / 256, 512, 0, stream>>>(x, blob, cbn, invn, out, lacc,
                                               rcnt, rlist, pkey, pv2b, tix);
    k_repair<<<1024,     256, 0, stream>>>(x, invn, cbn, out, rcnt, rlist, lacc, done);
}

// Round 11
// 617.705 us; speedup vs baseline: 2.7394x; 2.7394x over previous
//
#include <hip/hip_runtime.h>
#include <cstddef>

#define EPSF 1e-12f

constexpr int Bc = 16, Dc = 128, Lc = 4096, Kc = 4096;
constexpr int Nc = Bc * Lc;     // 65536
constexpr float TAU = 1e-4f;    // 2x split-bf16 err (~4e-5) + 8-bit pack err (~6e-5)
constexpr int RCAP = 32768;

typedef __attribute__((ext_vector_type(8))) short short8;
typedef __attribute__((ext_vector_type(4))) float f32x4;

__device__ __forceinline__ unsigned short f2bf(float f) {
    unsigned u = __float_as_uint(f);
    return (unsigned short)((u + 0x7fffu + ((u >> 16) & 1u)) >> 16);
}
__device__ __forceinline__ float bf2f(unsigned short u) {
    return __uint_as_float(((unsigned)u) << 16);
}

// ---------------------------------------------------------------------------
// Fused codebook prep: normalize -> cbn (f32) AND pack MFMA-operand blob.
// Blob layout: group g (16 codes) -> 8 frags (kd 0..3 x {hi,lo}) of 1024B;
// within a frag, 16B slot l = q*16 + (k&15) holds bf16 of dims (kd*4+q)*8..+7
// of code k. Zero-inits loss / repair counter / done (graph-replay safe).
// ---------------------------------------------------------------------------
__global__ void k_prep(const float* __restrict__ emb, float* __restrict__ cbn,
                       char* __restrict__ blob, float* __restrict__ lacc,
                       int* __restrict__ rcnt, int* __restrict__ done) {
    __shared__ float cls[4][128];
    const int tid  = threadIdx.x;
    const int w    = tid >> 6;
    const int lane = tid & 63;
    const int k    = (blockIdx.x << 2) + w;

    float2 v = ((const float2*)(emb + (size_t)k * Dc))[lane];
    float s = v.x * v.x + v.y * v.y;
    #pragma unroll
    for (int off = 32; off > 0; off >>= 1) s += __shfl_down(s, off);
    s = __shfl(s, 0);
    float inv = 1.f / fmaxf(sqrtf(s), EPSF);
    v.x *= inv; v.y *= inv;
    ((float2*)(cbn + (size_t)k * Dc))[lane] = v;
    cls[w][lane * 2]     = v.x;
    cls[w][lane * 2 + 1] = v.y;
    if (blockIdx.x == 0 && tid == 0) { *lacc = 0.f; *rcnt = 0; *done = 0; }
    __syncthreads();

    if (tid < 64) {           // 4 codes x 16 chunks
        int kl = tid >> 4, c = tid & 15;
        int kk = (blockIdx.x << 2) + kl;
        int kd = c >> 2, q = c & 3;
        short8 hh, ll;
        #pragma unroll
        for (int j = 0; j < 8; ++j) {
            float f = cls[kl][c * 8 + j];
            unsigned short hb = f2bf(f);
            hh[j] = (short)hb;
            ll[j] = (short)f2bf(f - bf2f(hb));
        }
        size_t base = (size_t)(kk >> 4) * 8192 + (size_t)(q * 16 + (kk & 15)) * 16;
        *(short8*)(blob + base + (kd * 2 + 0) * 1024) = hh;
        *(short8*)(blob + base + (kd * 2 + 1) * 1024) = ll;
    }
}

// ---------------------------------------------------------------------------
// MFMA argmax — exact round-9 structure (best measured: 177.8 us, MfmaUtil
// 53.5%, ~95% of the 16x16 MFMA issue ceiling at 2 waves/SIMD). Block =
// 512 thr / 8 waves = (4 rowsets x 2 codesets), 256 rows/block, grid 256.
// Barrier-free K-loop, blob L2-resident, global->VGPR ping-pong, med3
// second-best fold, setprio around the MFMA cluster.
// NOTE (r7/r10): launch_bounds(512,4) caps VGPR at 64 vs ~250 demand ->
// 3-4 GB spill. 2 waves/SIMD is the occupancy ceiling for this shape.
// Tail: LDS-transposed gather-write.
// ---------------------------------------------------------------------------
__global__ __launch_bounds__(512, 2)
void k_argmax(const float* __restrict__ x, const char* __restrict__ blob,
              const float* __restrict__ cbn, float* __restrict__ invn,
              float* __restrict__ out, float* __restrict__ lossacc,
              int* __restrict__ rcnt, int* __restrict__ rlist) {
    __shared__ __align__(16) char smem[33280];
    float* xt   = (float*)smem;              // [64][129] (preamble overlay)
    float* invl = (float*)(smem + 33024);    // [64]

    const int tid  = threadIdx.x;
    const int w    = tid >> 6;
    const int lane = tid & 63;
    const int m16  = lane & 15;
    const int quad = lane >> 4;
    const int rs   = w >> 1;      // rowset 0..3 (64 rows each)
    const int cs   = w & 1;       // codeset 0/1 (16 codes per tile)
    const int n0   = blockIdx.x * 256;
    const int bI   = n0 >> 12;
    const int l0   = n0 & (Lc - 1);
    const float* xb = x + (size_t)bI * Dc * Lc;

    // ---- preamble: 4 halves of 64 rows: transpose, normalize, build A frags
    short8 ah[4][4], al[4][4];
    for (int h = 0; h < 4; ++h) {
        __syncthreads();
        #pragma unroll
        for (int j = 0; j < 4; ++j) {
            int fl = tid + j * 512;              // 0..2047
            int d = fl >> 4, lq = fl & 15;
            float4 v = *(const float4*)(xb + (size_t)d * Lc + l0 + h * 64 + lq * 4);
            xt[(lq * 4 + 0) * 129 + d] = v.x;
            xt[(lq * 4 + 1) * 129 + d] = v.y;
            xt[(lq * 4 + 2) * 129 + d] = v.z;
            xt[(lq * 4 + 3) * 129 + d] = v.w;
        }
        __syncthreads();
        {   // row norms, 8 threads/row
            int row = tid >> 3, q = tid & 7;
            float s = 0.f;
            #pragma unroll
            for (int j = 0; j < 16; ++j) { float t = xt[row * 129 + q * 16 + j]; s += t * t; }
            s += __shfl_down(s, 1); s += __shfl_down(s, 2); s += __shfl_down(s, 4);
            if (q == 0) {
                float inv = 1.f / fmaxf(sqrtf(s), EPSF);
                invl[row] = inv;
                invn[n0 + h * 64 + row] = inv;
            }
        }
        __syncthreads();
        if (rs == h) {   // both cs-waves of this rowset build the frags
            #pragma unroll
            for (int rt = 0; rt < 4; ++rt) {
                int rl = rt * 16 + m16;          // A layout: m = lane&15
                float inv = invl[rl];
                #pragma unroll
                for (int kd = 0; kd < 4; ++kd) {
                    int dof = kd * 32 + quad * 8;   // k = quad*8 + j
                    short8 hhv, llv;
                    #pragma unroll
                    for (int j = 0; j < 8; ++j) {
                        float xn = xt[rl * 129 + dof + j] * inv;
                        unsigned short hb = f2bf(xn);
                        hhv[j] = (short)hb;
                        llv[j] = (short)f2bf(xn - bf2f(hb));
                    }
                    ah[rt][kd] = hhv; al[rt][kd] = llv;
                }
            }
        }
    }
    __syncthreads();

    // ---- K loop: 128 tiles of 32 codes (16 per codeset), barrier-free ----
    const f32x4 fz = {0.f, 0.f, 0.f, 0.f};
    float Bb[16], Ss[16];
    #pragma unroll
    for (int i = 0; i < 16; ++i) { Bb[i] = -3.0e38f; Ss[i] = -3.0e38f; }
    unsigned kc8 = (unsigned)cs;     // packed tag = code>>4 = t*2+cs

    const char* pb = blob + (size_t)cs * 8192 + (size_t)lane * 16;

    auto tileStep = [&](const short8* Bf) {
        f32x4 acc[4];
        __builtin_amdgcn_s_setprio(1);
        #pragma unroll
        for (int kd = 0; kd < 4; ++kd) {
            short8 bh = Bf[kd * 2];
            short8 bl = Bf[kd * 2 + 1];
            #pragma unroll
            for (int rt = 0; rt < 4; ++rt)
                acc[rt] = __builtin_amdgcn_mfma_f32_16x16x32_bf16(
                    ah[rt][kd], bh, (kd == 0) ? fz : acc[rt], 0, 0, 0);
            #pragma unroll
            for (int rt = 0; rt < 4; ++rt)
                acc[rt] = __builtin_amdgcn_mfma_f32_16x16x32_bf16(
                    ah[rt][kd], bl, acc[rt], 0, 0, 0);
            #pragma unroll
            for (int rt = 0; rt < 4; ++rt)
                acc[rt] = __builtin_amdgcn_mfma_f32_16x16x32_bf16(
                    al[rt][kd], bh, acc[rt], 0, 0, 0);
        }
        __builtin_amdgcn_s_setprio(0);
        // fold: Ss <= Bb invariant -> med3(Bb, p, Ss) is exact second-best.
        #pragma unroll
        for (int rt = 0; rt < 4; ++rt)
            #pragma unroll
            for (int rg = 0; rg < 4; ++rg) {
                int s = rt * 4 + rg;
                float p = __uint_as_float(
                    (__float_as_uint(acc[rt][rg]) & 0xFFFFFF00u) | kc8);
                Ss[s] = __builtin_amdgcn_fmed3f(Bb[s], p, Ss[s]);
                Bb[s] = fmaxf(Bb[s], p);
            }
        kc8 += 2;
    };

    short8 bA[8], bB[8];
    #pragma unroll
    for (int f = 0; f < 8; ++f) bA[f] = *(const short8*)(pb + f * 1024);

    for (int tt = 0; tt < 64; ++tt) {
        {   // even tile t = 2*tt: prefetch t+1 into bB, compute bA
            const int t = 2 * tt;
            const char* p = pb + (size_t)(t + 1) * 16384;
            #pragma unroll
            for (int f = 0; f < 8; ++f) bB[f] = *(const short8*)(p + f * 1024);
            tileStep(bA);
        }
        {   // odd tile t = 2*tt+1: prefetch t+1 into bA (clamp last), compute bB
            const int t = 2 * tt + 1;
            const size_t tn = (t < 127) ? (size_t)(t + 1) : (size_t)t;
            const char* p = pb + tn * 16384;
            #pragma unroll
            for (int f = 0; f < 8; ++f) bA[f] = *(const short8*)(p + f * 1024);
            tileStep(bB);
        }
    }

    // ---- epilogue: merge 16 m16-lanes per slot ----
    float mv1[16], mv2[16]; int mk1[16];
    #pragma unroll
    for (int s = 0; s < 16; ++s) {
        float v1 = Bb[s], v2 = Ss[s];
        int k1 = (int)(((__float_as_uint(v1) & 0xFFu) << 4) | (unsigned)m16);
        #pragma unroll
        for (int off = 1; off < 16; off <<= 1) {
            float ov1 = __shfl_xor(v1, off);
            float ov2 = __shfl_xor(v2, off);
            int   ok1 = __shfl_xor(k1, off);
            bool gt = ov1 > v1, eq = ov1 == v1;
            v2 = gt ? fmaxf(ov2, v1) : fmaxf(v2, ov1);
            v1 = gt ? ov1 : v1;
            k1 = gt ? ok1 : (eq ? min(k1, ok1) : k1);
        }
        mv1[s] = v1; mv2[s] = v2; mk1[s] = k1;
    }
    // cross-codeset merge via LDS: [256 rows][2 cs]
    float* Ev = (float*)smem;                // 2048 B
    float* Sv = (float*)(smem + 2048);
    int*   Kv = (int*)(smem + 4096);
    float* bsum = (float*)(smem + 6144);
    int*   sidx = (int*)(smem + 8192);       // [256] final code per row
    __syncthreads();
    if (tid == 0) *bsum = 0.f;
    if (m16 == 0) {
        #pragma unroll
        for (int s = 0; s < 16; ++s) {
            int rt = s >> 2, rg = s & 3;
            int row = rs * 64 + rt * 16 + quad * 4 + rg;   // C row = quad*4+reg
            Ev[row * 2 + cs] = mv1[s];
            Sv[row * 2 + cs] = mv2[s];
            Kv[row * 2 + cs] = mk1[s];
        }
    }
    __syncthreads();
    if (tid < 256) {
        float v1 = Ev[tid * 2], v2 = Sv[tid * 2];
        int   k1 = Kv[tid * 2];
        float ov1 = Ev[tid * 2 + 1], ov2 = Sv[tid * 2 + 1];
        int   ok1 = Kv[tid * 2 + 1];
        bool gt = ov1 > v1, eq = ov1 == v1;
        v2 = gt ? fmaxf(ov2, v1) : fmaxf(v2, ov1);
        v1 = gt ? ov1 : v1;
        k1 = gt ? ok1 : (eq ? min(k1, ok1) : k1);
        sidx[tid] = k1;
        atomicAdd(bsum, v1);
        if (v1 - v2 < TAU) {
            int pos = atomicAdd(rcnt, 1);
            if (pos < RCAP) rlist[pos] = n0 + tid;
        }
    }
    __syncthreads();
    if (tid == 0) atomicAdd(lossacc, *bsum);

    // ---- fused output write via LDS transpose: 4 chunks of 64 rows.
    int myk[4];
    #pragma unroll
    for (int c = 0; c < 4; ++c) myk[c] = sidx[c * 64 + (tid >> 3)];
    float* tb = (float*)smem;                // [64][130] = 33280 B
    float* ob = out + (size_t)bI * Dc * Lc + l0;
    #pragma unroll 1
    for (int c = 0; c < 4; ++c) {
        __syncthreads();                     // prior chunk reads / sidx done
        {
            const float4* src = (const float4*)(cbn + (size_t)myk[c] * Dc + (tid & 7) * 16);
            float4 v0 = src[0], v1 = src[1], v2 = src[2], v3 = src[3];
            float* dst = tb + (tid >> 3) * 130 + (tid & 7) * 16;
            *(float4*)(dst + 0)  = v0;
            *(float4*)(dst + 4)  = v1;
            *(float4*)(dst + 8)  = v2;
            *(float4*)(dst + 12) = v3;
        }
        __syncthreads();
        {
            int l = tid & 63, d0 = tid >> 6;     // wave = fixed d, l 0..63
            #pragma unroll
            for (int dd = 0; dd < 16; ++dd) {
                int d = d0 * 16 + dd;
                ob[(size_t)d * Lc + c * 64 + l] = tb[l * 130 + d];
            }
        }
    }
}

// ---------------------------------------------------------------------------
// Exact fp32 re-argmax, 8-query batched: one codebook pass serves 8 flagged
// queries (LDS-staged, broadcast reads) -> cbn L2 traffic / 8. Per-(query,
// code) fmaf chain, ascending-k visit, '>' (min-k) tie-break, and packed-key
// wave reduction identical to the unbatched version. Rewrites out rows;
// last block (device-scope done counter) writes the scalar loss.
// ---------------------------------------------------------------------------
__global__ __launch_bounds__(256)
void k_repair(const float* __restrict__ x, const float* __restrict__ invn,
              const float* __restrict__ cbn, float* __restrict__ out,
              const int* __restrict__ rcnt, const int* __restrict__ rlist,
              const float* __restrict__ lacc, int* __restrict__ done) {
    __shared__ float xs[8][132];
    __shared__ unsigned long long red[8][4];
    __shared__ int fks[8];
    int cnt = *rcnt; if (cnt > RCAP) cnt = RCAP;
    const int tid = threadIdx.x;
    const int ngrp = (cnt + 7) >> 3;

    for (int g = blockIdx.x; g < ngrp; g += gridDim.x) {
        const int base = g * 8;
        __syncthreads();     // xs/red/fks from previous group fully consumed
        {   // stage 8 normalized query rows: thread t -> (q = t>>5, 4 dims)
            int q  = tid >> 5;
            int dd = (tid & 31) * 4;
            int idx = base + q;
            int n = rlist[(idx < cnt) ? idx : (cnt - 1)];
            int b = n >> 12, l = n & (Lc - 1);
            float inv = invn[n];
            const float* xp = x + (size_t)b * Dc * Lc + l;
            xs[q][dd + 0] = xp[(size_t)(dd + 0) * Lc] * inv;
            xs[q][dd + 1] = xp[(size_t)(dd + 1) * Lc] * inv;
            xs[q][dd + 2] = xp[(size_t)(dd + 2) * Lc] * inv;
            xs[q][dd + 3] = xp[(size_t)(dd + 3) * Lc] * inv;
        }
        __syncthreads();

        float best[8]; int bk[8];
        #pragma unroll
        for (int q = 0; q < 8; ++q) { best[q] = -3.0e38f; bk[q] = 0; }
        #pragma unroll 1
        for (int i = 0; i < 16; ++i) {
            int k = i * 256 + tid;            // ascending: '>' keeps min k
            const float4* cr = (const float4*)(cbn + (size_t)k * Dc);
            float s[8];
            #pragma unroll
            for (int q = 0; q < 8; ++q) s[q] = 0.f;
            #pragma unroll
            for (int j = 0; j < 32; ++j) {
                float4 c = cr[j];
                #pragma unroll
                for (int q = 0; q < 8; ++q) {
                    s[q] = fmaf(c.x, xs[q][j * 4 + 0], s[q]);
                    s[q] = fmaf(c.y, xs[q][j * 4 + 1], s[q]);
                    s[q] = fmaf(c.z, xs[q][j * 4 + 2], s[q]);
                    s[q] = fmaf(c.w, xs[q][j * 4 + 3], s[q]);
                }
            }
            #pragma unroll
            for (int q = 0; q < 8; ++q)
                if (s[q] > best[q]) { best[q] = s[q]; bk[q] = k; }
        }
        // per-query cross-thread reduce (packed key: max v1, tie -> min k)
        #pragma unroll
        for (int q = 0; q < 8; ++q) {
            unsigned kb = __float_as_uint(best[q]);
            kb = (kb & 0x80000000u) ? ~kb : (kb | 0x80000000u);
            unsigned long long pk =
                ((unsigned long long)kb << 32) | (unsigned)(0xFFFFFFFFu - (unsigned)bk[q]);
            #pragma unroll
            for (int off = 32; off >= 1; off >>= 1) {
                unsigned long long o = __shfl_xor(pk, off);
                pk = (o > pk) ? o : pk;
            }
            if ((tid & 63) == 0) red[q][tid >> 6] = pk;
        }
        __syncthreads();
        if (tid < 8) {
            unsigned long long m = red[tid][0];
            #pragma unroll
            for (int i = 1; i < 4; ++i) if (red[tid][i] > m) m = red[tid][i];
            fks[tid] = (int)(0xFFFFFFFFu - (unsigned)(m & 0xFFFFFFFFull));
        }
        __syncthreads();
        {   // rewrite out rows with the exact codes
            int q  = tid >> 5;
            int dd = (tid & 31) * 4;
            int idx = base + q;
            if (idx < cnt) {
                int n = rlist[idx];
                int b = n >> 12, l = n & (Lc - 1);
                const float* cr = cbn + (size_t)fks[q] * Dc;
                float* op = out + (size_t)b * Dc * Lc + l;
                op[(size_t)(dd + 0) * Lc] = cr[dd + 0];
                op[(size_t)(dd + 1) * Lc] = cr[dd + 1];
                op[(size_t)(dd + 2) * Lc] = cr[dd + 2];
                op[(size_t)(dd + 3) * Lc] = cr[dd + 3];
            }
        }
    }
    // ---- fused loss finalize: last block writes the scalar
    __syncthreads();
    if (tid == 0) {
        int old = atomicAdd(done, 1);
        if (old == (int)gridDim.x - 1)
            out[(size_t)Bc * Dc * Lc] = 2.0f - 2.0f * (*lacc) / (float)Nc;
    }
}

// ---------------------------------------------------------------------------
extern "C" void kernel_launch(void* const* d_in, const int* in_sizes, int n_in,
                              void* d_out, int out_size, void* d_ws, size_t ws_size,
                              hipStream_t stream) {
    const float* x   = (const float*)d_in[0];   // [16][128][4096] fp32
    const float* emb = (const float*)d_in[1];   // [4096][128] fp32
    float* out = (float*)d_out;

    char* ws = (char*)d_ws;
    float* cbn  = (float*)ws;                                  // 2 MB
    char*  blob = ws + (2u << 20);                             // 2 MB
    float* invn = (float*)(ws + (4u << 20));                   // 256 KB
    char*  b5   = ws + (4u << 20) + (512u << 10);
    float* lacc = (float*)b5;
    int*   rcnt = (int*)(b5 + 64);
    int*   done = (int*)(b5 + 128);
    int*   rlist= (int*)(b5 + 1024);                           // 128 KB

    k_prep  <<<Kc / 4,   256, 0, stream>>>(emb, cbn, blob, lacc, rcnt, done);
    k_argmax<<<Nc / 256, 512, 0, stream>>>(x, blob, cbn, invn, out, lacc, rcnt, rlist);
    k_repair<<<1024,     256, 0, stream>>>(x, invn, cbn, out, rcnt, rlist, lacc, done);
}

// Round 12
// 553.504 us; speedup vs baseline: 3.0572x; 1.1160x over previous
//
#include <hip/hip_runtime.h>
#include <cstddef>

#define EPSF 1e-12f

constexpr int Bc = 16, Dc = 128, Lc = 4096, Kc = 4096;
constexpr int Nc = Bc * Lc;     // 65536
constexpr float TAU = 1e-4f;    // 2x split-bf16 err (~4e-5) + 8-bit pack err (~6e-5)
constexpr int RCAP = 32768;

typedef __attribute__((ext_vector_type(8))) short short8;
typedef __attribute__((ext_vector_type(4))) float f32x4;

__device__ __forceinline__ unsigned short f2bf(float f) {
    unsigned u = __float_as_uint(f);
    return (unsigned short)((u + 0x7fffu + ((u >> 16) & 1u)) >> 16);
}
__device__ __forceinline__ float bf2f(unsigned short u) {
    return __uint_as_float(((unsigned)u) << 16);
}

// ---------------------------------------------------------------------------
// Fused codebook prep: normalize -> cbn (f32) AND pack MFMA-operand blob.
// Blob layout: group g (16 codes) -> 8 frags (kd 0..3 x {hi,lo}) of 1024B;
// within a frag, 16B slot l = q*16 + (k&15) holds bf16 of dims (kd*4+q)*8..+7
// of code k. Zero-inits loss / repair counter / done / pkey / qdone
// (graph-replay safe).
// ---------------------------------------------------------------------------
__global__ void k_prep(const float* __restrict__ emb, float* __restrict__ cbn,
                       char* __restrict__ blob, float* __restrict__ lacc,
                       int* __restrict__ rcnt, int* __restrict__ done,
                       unsigned long long* __restrict__ pkey,
                       int* __restrict__ qdone) {
    __shared__ float cls[4][128];
    const int tid  = threadIdx.x;
    const int w    = tid >> 6;
    const int lane = tid & 63;
    const int k    = (blockIdx.x << 2) + w;

    // zero repair-merge state (first 128 blocks cover RCAP entries)
    int gid = blockIdx.x * 256 + tid;
    if (gid < RCAP) { pkey[gid] = 0ull; qdone[gid] = 0; }

    float2 v = ((const float2*)(emb + (size_t)k * Dc))[lane];
    float s = v.x * v.x + v.y * v.y;
    #pragma unroll
    for (int off = 32; off > 0; off >>= 1) s += __shfl_down(s, off);
    s = __shfl(s, 0);
    float inv = 1.f / fmaxf(sqrtf(s), EPSF);
    v.x *= inv; v.y *= inv;
    ((float2*)(cbn + (size_t)k * Dc))[lane] = v;
    cls[w][lane * 2]     = v.x;
    cls[w][lane * 2 + 1] = v.y;
    if (blockIdx.x == 0 && tid == 0) { *lacc = 0.f; *rcnt = 0; *done = 0; }
    __syncthreads();

    if (tid < 64) {           // 4 codes x 16 chunks
        int kl = tid >> 4, c = tid & 15;
        int kk = (blockIdx.x << 2) + kl;
        int kd = c >> 2, q = c & 3;
        short8 hh, ll;
        #pragma unroll
        for (int j = 0; j < 8; ++j) {
            float f = cls[kl][c * 8 + j];
            unsigned short hb = f2bf(f);
            hh[j] = (short)hb;
            ll[j] = (short)f2bf(f - bf2f(hb));
        }
        size_t base = (size_t)(kk >> 4) * 8192 + (size_t)(q * 16 + (kk & 15)) * 16;
        *(short8*)(blob + base + (kd * 2 + 0) * 1024) = hh;
        *(short8*)(blob + base + (kd * 2 + 1) * 1024) = ll;
    }
}

// ---------------------------------------------------------------------------
// MFMA argmax — exact round-9 structure (best measured: 177.8 us, MfmaUtil
// 53.5%, ~95% of the 16x16 MFMA issue ceiling at 2 waves/SIMD). Block =
// 512 thr / 8 waves = (4 rowsets x 2 codesets), 256 rows/block, grid 256.
// Barrier-free K-loop, blob L2-resident, global->VGPR ping-pong, med3
// second-best fold, setprio around the MFMA cluster.
// NOTE (r7/r10): raising min-waves caps VGPR far below the ~250-reg demand
// -> multi-GB spill. 2 waves/SIMD is the occupancy ceiling for this shape.
// Tail: LDS-transposed gather-write.
// ---------------------------------------------------------------------------
__global__ __launch_bounds__(512, 2)
void k_argmax(const float* __restrict__ x, const char* __restrict__ blob,
              const float* __restrict__ cbn, float* __restrict__ invn,
              float* __restrict__ out, float* __restrict__ lossacc,
              int* __restrict__ rcnt, int* __restrict__ rlist) {
    __shared__ __align__(16) char smem[33280];
    float* xt   = (float*)smem;              // [64][129] (preamble overlay)
    float* invl = (float*)(smem + 33024);    // [64]

    const int tid  = threadIdx.x;
    const int w    = tid >> 6;
    const int lane = tid & 63;
    const int m16  = lane & 15;
    const int quad = lane >> 4;
    const int rs   = w >> 1;      // rowset 0..3 (64 rows each)
    const int cs   = w & 1;       // codeset 0/1 (16 codes per tile)
    const int n0   = blockIdx.x * 256;
    const int bI   = n0 >> 12;
    const int l0   = n0 & (Lc - 1);
    const float* xb = x + (size_t)bI * Dc * Lc;

    // ---- preamble: 4 halves of 64 rows: transpose, normalize, build A frags
    short8 ah[4][4], al[4][4];
    for (int h = 0; h < 4; ++h) {
        __syncthreads();
        #pragma unroll
        for (int j = 0; j < 4; ++j) {
            int fl = tid + j * 512;              // 0..2047
            int d = fl >> 4, lq = fl & 15;
            float4 v = *(const float4*)(xb + (size_t)d * Lc + l0 + h * 64 + lq * 4);
            xt[(lq * 4 + 0) * 129 + d] = v.x;
            xt[(lq * 4 + 1) * 129 + d] = v.y;
            xt[(lq * 4 + 2) * 129 + d] = v.z;
            xt[(lq * 4 + 3) * 129 + d] = v.w;
        }
        __syncthreads();
        {   // row norms, 8 threads/row
            int row = tid >> 3, q = tid & 7;
            float s = 0.f;
            #pragma unroll
            for (int j = 0; j < 16; ++j) { float t = xt[row * 129 + q * 16 + j]; s += t * t; }
            s += __shfl_down(s, 1); s += __shfl_down(s, 2); s += __shfl_down(s, 4);
            if (q == 0) {
                float inv = 1.f / fmaxf(sqrtf(s), EPSF);
                invl[row] = inv;
                invn[n0 + h * 64 + row] = inv;
            }
        }
        __syncthreads();
        if (rs == h) {   // both cs-waves of this rowset build the frags
            #pragma unroll
            for (int rt = 0; rt < 4; ++rt) {
                int rl = rt * 16 + m16;          // A layout: m = lane&15
                float inv = invl[rl];
                #pragma unroll
                for (int kd = 0; kd < 4; ++kd) {
                    int dof = kd * 32 + quad * 8;   // k = quad*8 + j
                    short8 hhv, llv;
                    #pragma unroll
                    for (int j = 0; j < 8; ++j) {
                        float xn = xt[rl * 129 + dof + j] * inv;
                        unsigned short hb = f2bf(xn);
                        hhv[j] = (short)hb;
                        llv[j] = (short)f2bf(xn - bf2f(hb));
                    }
                    ah[rt][kd] = hhv; al[rt][kd] = llv;
                }
            }
        }
    }
    __syncthreads();

    // ---- K loop: 128 tiles of 32 codes (16 per codeset), barrier-free ----
    const f32x4 fz = {0.f, 0.f, 0.f, 0.f};
    float Bb[16], Ss[16];
    #pragma unroll
    for (int i = 0; i < 16; ++i) { Bb[i] = -3.0e38f; Ss[i] = -3.0e38f; }
    unsigned kc8 = (unsigned)cs;     // packed tag = code>>4 = t*2+cs

    const char* pb = blob + (size_t)cs * 8192 + (size_t)lane * 16;

    auto tileStep = [&](const short8* Bf) {
        f32x4 acc[4];
        __builtin_amdgcn_s_setprio(1);
        #pragma unroll
        for (int kd = 0; kd < 4; ++kd) {
            short8 bh = Bf[kd * 2];
            short8 bl = Bf[kd * 2 + 1];
            #pragma unroll
            for (int rt = 0; rt < 4; ++rt)
                acc[rt] = __builtin_amdgcn_mfma_f32_16x16x32_bf16(
                    ah[rt][kd], bh, (kd == 0) ? fz : acc[rt], 0, 0, 0);
            #pragma unroll
            for (int rt = 0; rt < 4; ++rt)
                acc[rt] = __builtin_amdgcn_mfma_f32_16x16x32_bf16(
                    ah[rt][kd], bl, acc[rt], 0, 0, 0);
            #pragma unroll
            for (int rt = 0; rt < 4; ++rt)
                acc[rt] = __builtin_amdgcn_mfma_f32_16x16x32_bf16(
                    al[rt][kd], bh, acc[rt], 0, 0, 0);
        }
        __builtin_amdgcn_s_setprio(0);
        // fold: Ss <= Bb invariant -> med3(Bb, p, Ss) is exact second-best.
        #pragma unroll
        for (int rt = 0; rt < 4; ++rt)
            #pragma unroll
            for (int rg = 0; rg < 4; ++rg) {
                int s = rt * 4 + rg;
                float p = __uint_as_float(
                    (__float_as_uint(acc[rt][rg]) & 0xFFFFFF00u) | kc8);
                Ss[s] = __builtin_amdgcn_fmed3f(Bb[s], p, Ss[s]);
                Bb[s] = fmaxf(Bb[s], p);
            }
        kc8 += 2;
    };

    short8 bA[8], bB[8];
    #pragma unroll
    for (int f = 0; f < 8; ++f) bA[f] = *(const short8*)(pb + f * 1024);

    for (int tt = 0; tt < 64; ++tt) {
        {   // even tile t = 2*tt: prefetch t+1 into bB, compute bA
            const int t = 2 * tt;
            const char* p = pb + (size_t)(t + 1) * 16384;
            #pragma unroll
            for (int f = 0; f < 8; ++f) bB[f] = *(const short8*)(p + f * 1024);
            tileStep(bA);
        }
        {   // odd tile t = 2*tt+1: prefetch t+1 into bA (clamp last), compute bB
            const int t = 2 * tt + 1;
            const size_t tn = (t < 127) ? (size_t)(t + 1) : (size_t)t;
            const char* p = pb + tn * 16384;
            #pragma unroll
            for (int f = 0; f < 8; ++f) bA[f] = *(const short8*)(p + f * 1024);
            tileStep(bB);
        }
    }

    // ---- epilogue: merge 16 m16-lanes per slot ----
    float mv1[16], mv2[16]; int mk1[16];
    #pragma unroll
    for (int s = 0; s < 16; ++s) {
        float v1 = Bb[s], v2 = Ss[s];
        int k1 = (int)(((__float_as_uint(v1) & 0xFFu) << 4) | (unsigned)m16);
        #pragma unroll
        for (int off = 1; off < 16; off <<= 1) {
            float ov1 = __shfl_xor(v1, off);
            float ov2 = __shfl_xor(v2, off);
            int   ok1 = __shfl_xor(k1, off);
            bool gt = ov1 > v1, eq = ov1 == v1;
            v2 = gt ? fmaxf(ov2, v1) : fmaxf(v2, ov1);
            v1 = gt ? ov1 : v1;
            k1 = gt ? ok1 : (eq ? min(k1, ok1) : k1);
        }
        mv1[s] = v1; mv2[s] = v2; mk1[s] = k1;
    }
    // cross-codeset merge via LDS: [256 rows][2 cs]
    float* Ev = (float*)smem;                // 2048 B
    float* Sv = (float*)(smem + 2048);
    int*   Kv = (int*)(smem + 4096);
    float* bsum = (float*)(smem + 6144);
    int*   sidx = (int*)(smem + 8192);       // [256] final code per row
    __syncthreads();
    if (tid == 0) *bsum = 0.f;
    if (m16 == 0) {
        #pragma unroll
        for (int s = 0; s < 16; ++s) {
            int rt = s >> 2, rg = s & 3;
            int row = rs * 64 + rt * 16 + quad * 4 + rg;   // C row = quad*4+reg
            Ev[row * 2 + cs] = mv1[s];
            Sv[row * 2 + cs] = mv2[s];
            Kv[row * 2 + cs] = mk1[s];
        }
    }
    __syncthreads();
    if (tid < 256) {
        float v1 = Ev[tid * 2], v2 = Sv[tid * 2];
        int   k1 = Kv[tid * 2];
        float ov1 = Ev[tid * 2 + 1], ov2 = Sv[tid * 2 + 1];
        int   ok1 = Kv[tid * 2 + 1];
        bool gt = ov1 > v1, eq = ov1 == v1;
        v2 = gt ? fmaxf(ov2, v1) : fmaxf(v2, ov1);
        v1 = gt ? ov1 : v1;
        k1 = gt ? ok1 : (eq ? min(k1, ok1) : k1);
        sidx[tid] = k1;
        atomicAdd(bsum, v1);
        if (v1 - v2 < TAU) {
            int pos = atomicAdd(rcnt, 1);
            if (pos < RCAP) rlist[pos] = n0 + tid;
        }
    }
    __syncthreads();
    if (tid == 0) atomicAdd(lossacc, *bsum);

    // ---- fused output write via LDS transpose: 4 chunks of 64 rows.
    int myk[4];
    #pragma unroll
    for (int c = 0; c < 4; ++c) myk[c] = sidx[c * 64 + (tid >> 3)];
    float* tb = (float*)smem;                // [64][130] = 33280 B
    float* ob = out + (size_t)bI * Dc * Lc + l0;
    #pragma unroll 1
    for (int c = 0; c < 4; ++c) {
        __syncthreads();                     // prior chunk reads / sidx done
        {
            const float4* src = (const float4*)(cbn + (size_t)myk[c] * Dc + (tid & 7) * 16);
            float4 v0 = src[0], v1 = src[1], v2 = src[2], v3 = src[3];
            float* dst = tb + (tid >> 3) * 130 + (tid & 7) * 16;
            *(float4*)(dst + 0)  = v0;
            *(float4*)(dst + 4)  = v1;
            *(float4*)(dst + 8)  = v2;
            *(float4*)(dst + 12) = v3;
        }
        __syncthreads();
        {
            int l = tid & 63, d0 = tid >> 6;     // wave = fixed d, l 0..63
            #pragma unroll
            for (int dd = 0; dd < 16; ++dd) {
                int d = d0 * 16 + dd;
                ob[(size_t)d * Lc + c * 64 + l] = tb[l * 130 + d];
            }
        }
    }
}

// ---------------------------------------------------------------------------
// Exact fp32 re-argmax: (8-query group) x (8-way K-split) pairs, grid-stride
// over ngrp*8 pairs with 2048 blocks -> ~8x less L2 traffic than unbatched
// AND full parallelism (r11's batched version had 140 blocks, 1.9% occ).
// Each block: stage 8 rows in LDS, dot 512 codes x 8 queries, block-reduce
// per query to a packed (v1|~k) key, publish via device-scope atomicMax
// (exact max-v1/min-k merge, partition-order independent), ticket
// atomicAdd(qdone); 8th finisher writes the output row. No spinning.
// Last grid block (done counter) writes the scalar loss.
// ---------------------------------------------------------------------------
__global__ __launch_bounds__(256, 4)
void k_repair(const float* __restrict__ x, const float* __restrict__ invn,
              const float* __restrict__ cbn, float* __restrict__ out,
              const int* __restrict__ rcnt, const int* __restrict__ rlist,
              const float* __restrict__ lacc, int* __restrict__ done,
              unsigned long long* __restrict__ pkey, int* __restrict__ qdone) {
    __shared__ float4 xs4[8][32];            // 8 normalized query rows
    __shared__ unsigned long long red[8][4];
    __shared__ int nsh[8];
    __shared__ int wq[8];
    __shared__ int fkq[8];
    int cnt = *rcnt; if (cnt > RCAP) cnt = RCAP;
    const int tid = threadIdx.x;
    const int ngrp = (cnt + 7) >> 3;
    const int npair = ngrp * 8;

    for (int p = blockIdx.x; p < npair; p += gridDim.x) {
        const int g  = p >> 3;
        const int sp = p & 7;
        __syncthreads();     // previous pair's LDS fully consumed
        {   // stage: q = tid>>5, dims (tid&31)*4 .. +3
            int q  = tid >> 5;
            int dd = (tid & 31) << 2;
            int idx = g * 8 + q;
            if (idx < cnt) {
                int n = rlist[idx];
                int b = n >> 12, l = n & (Lc - 1);
                float inv = invn[n];
                const float* xp = x + (size_t)b * Dc * Lc + l;
                float4 v;
                v.x = xp[(size_t)(dd + 0) * Lc] * inv;
                v.y = xp[(size_t)(dd + 1) * Lc] * inv;
                v.z = xp[(size_t)(dd + 2) * Lc] * inv;
                v.w = xp[(size_t)(dd + 3) * Lc] * inv;
                xs4[q][tid & 31] = v;
                if (dd == 0) nsh[q] = n;
            } else {
                xs4[q][tid & 31] = make_float4(0.f, 0.f, 0.f, 0.f);
            }
        }
        __syncthreads();

        float best[8]; int bk[8];
        #pragma unroll
        for (int q = 0; q < 8; ++q) { best[q] = -3.0e38f; bk[q] = 0; }
        #pragma unroll 1
        for (int i = 0; i < 2; ++i) {
            int k = sp * 512 + i * 256 + tid;   // ascending: '>' keeps min k
            const float4* cr = (const float4*)(cbn + (size_t)k * Dc);
            float s[8];
            #pragma unroll
            for (int q = 0; q < 8; ++q) s[q] = 0.f;
            #pragma unroll
            for (int j = 0; j < 32; ++j) {
                float4 c = cr[j];
                #pragma unroll
                for (int q = 0; q < 8; ++q) {
                    float4 xv = xs4[q][j];
                    s[q] = fmaf(c.x, xv.x, s[q]); s[q] = fmaf(c.y, xv.y, s[q]);
                    s[q] = fmaf(c.z, xv.z, s[q]); s[q] = fmaf(c.w, xv.w, s[q]);
                }
            }
            #pragma unroll
            for (int q = 0; q < 8; ++q)
                if (s[q] > best[q]) { best[q] = s[q]; bk[q] = k; }
        }
        // per-query block reduce (packed key: max v1, tie -> min k)
        #pragma unroll
        for (int q = 0; q < 8; ++q) {
            unsigned kb = __float_as_uint(best[q]);
            kb = (kb & 0x80000000u) ? ~kb : (kb | 0x80000000u);
            unsigned long long pk =
                ((unsigned long long)kb << 32) | (unsigned)(0xFFFFFFFFu - (unsigned)bk[q]);
            #pragma unroll
            for (int off = 32; off >= 1; off >>= 1) {
                unsigned long long o = __shfl_xor(pk, off);
                pk = (o > pk) ? o : pk;
            }
            if ((tid & 63) == 0) red[q][tid >> 6] = pk;
        }
        __syncthreads();
        if (tid < 8) {
            wq[tid] = 0;
            int e = g * 8 + tid;
            if (e < cnt) {
                unsigned long long m = red[tid][0];
                #pragma unroll
                for (int i = 1; i < 4; ++i) if (red[tid][i] > m) m = red[tid][i];
                atomicMax(&pkey[e], m);
                __threadfence();
                int old = atomicAdd(&qdone[e], 1);
                if (old == 7) {      // all 8 splits published: final is ready
                    unsigned long long fin = atomicMax(&pkey[e], 0ull);
                    fkq[tid] = (int)(0xFFFFFFFFu - (unsigned)(fin & 0xFFFFFFFFull));
                    wq[tid] = 1;
                }
            }
        }
        __syncthreads();
        #pragma unroll 1
        for (int q = 0; q < 8; ++q) {
            if (wq[q] && tid < 128) {
                int n = nsh[q];
                int b = n >> 12, l = n & (Lc - 1);
                out[(size_t)b * Dc * Lc + (size_t)tid * Lc + l] =
                    cbn[(size_t)fkq[q] * Dc + tid];
            }
        }
    }
    // ---- fused loss finalize: last block writes the scalar
    __syncthreads();
    if (tid == 0) {
        int old = atomicAdd(done, 1);
        if (old == (int)gridDim.x - 1)
            out[(size_t)Bc * Dc * Lc] = 2.0f - 2.0f * (*lacc) / (float)Nc;
    }
}

// ---------------------------------------------------------------------------
extern "C" void kernel_launch(void* const* d_in, const int* in_sizes, int n_in,
                              void* d_out, int out_size, void* d_ws, size_t ws_size,
                              hipStream_t stream) {
    const float* x   = (const float*)d_in[0];   // [16][128][4096] fp32
    const float* emb = (const float*)d_in[1];   // [4096][128] fp32
    float* out = (float*)d_out;

    char* ws = (char*)d_ws;
    float* cbn  = (float*)ws;                                  // 2 MB
    char*  blob = ws + (2u << 20);                             // 2 MB
    float* invn = (float*)(ws + (4u << 20));                   // 256 KB
    char*  b5   = ws + (4u << 20) + (512u << 10);
    float* lacc = (float*)b5;
    int*   rcnt = (int*)(b5 + 64);
    int*   done = (int*)(b5 + 128);
    int*   rlist= (int*)(b5 + 1024);                           // 128 KB
    unsigned long long* pkey = (unsigned long long*)(ws + (5u << 20)); // 256 KB
    int*   qdone = (int*)(ws + (5u << 20) + (256u << 10));     // 128 KB

    k_prep  <<<Kc / 4,   256, 0, stream>>>(emb, cbn, blob, lacc, rcnt, done,
                                           pkey, qdone);
    k_argmax<<<Nc / 256, 512, 0, stream>>>(x, blob, cbn, invn, out, lacc, rcnt, rlist);
    k_repair<<<2048,     256, 0, stream>>>(x, invn, cbn, out, rcnt, rlist, lacc,
                                           done, pkey, qdone);
}

// Round 13
// 391.933 us; speedup vs baseline: 4.3175x; 1.4122x over previous
//
#include <hip/hip_runtime.h>
#include <cstddef>

#define EPSF 1e-12f

constexpr int Bc = 16, Dc = 128, Lc = 4096, Kc = 4096;
constexpr int Nc = Bc * Lc;     // 65536
constexpr float TAU = 1e-4f;    // 2x split-bf16 err (~4e-5) + 8-bit pack err (~6e-5)
constexpr int RCAP = 32768;

typedef __attribute__((ext_vector_type(8))) short short8;
typedef __attribute__((ext_vector_type(4))) float f32x4;

__device__ __forceinline__ unsigned short f2bf(float f) {
    unsigned u = __float_as_uint(f);
    return (unsigned short)((u + 0x7fffu + ((u >> 16) & 1u)) >> 16);
}
__device__ __forceinline__ float bf2f(unsigned short u) {
    return __uint_as_float(((unsigned)u) << 16);
}

// ---------------------------------------------------------------------------
// Fused codebook prep: normalize -> cbn (f32) AND pack MFMA-operand blob.
// Blob layout: group g (16 codes) -> 8 frags (kd 0..3 x {hi,lo}) of 1024B;
// within a frag, 16B slot l = q*16 + (k&15) holds bf16 of dims (kd*4+q)*8..+7
// of code k. Zero-inits loss / repair counter / done (graph-replay safe).
// ---------------------------------------------------------------------------
__global__ void k_prep(const float* __restrict__ emb, float* __restrict__ cbn,
                       char* __restrict__ blob, float* __restrict__ lacc,
                       int* __restrict__ rcnt, int* __restrict__ done) {
    __shared__ float cls[4][128];
    const int tid  = threadIdx.x;
    const int w    = tid >> 6;
    const int lane = tid & 63;
    const int k    = (blockIdx.x << 2) + w;

    float2 v = ((const float2*)(emb + (size_t)k * Dc))[lane];
    float s = v.x * v.x + v.y * v.y;
    #pragma unroll
    for (int off = 32; off > 0; off >>= 1) s += __shfl_down(s, off);
    s = __shfl(s, 0);
    float inv = 1.f / fmaxf(sqrtf(s), EPSF);
    v.x *= inv; v.y *= inv;
    ((float2*)(cbn + (size_t)k * Dc))[lane] = v;
    cls[w][lane * 2]     = v.x;
    cls[w][lane * 2 + 1] = v.y;
    if (blockIdx.x == 0 && tid == 0) { *lacc = 0.f; *rcnt = 0; *done = 0; }
    __syncthreads();

    if (tid < 64) {           // 4 codes x 16 chunks
        int kl = tid >> 4, c = tid & 15;
        int kk = (blockIdx.x << 2) + kl;
        int kd = c >> 2, q = c & 3;
        short8 hh, ll;
        #pragma unroll
        for (int j = 0; j < 8; ++j) {
            float f = cls[kl][c * 8 + j];
            unsigned short hb = f2bf(f);
            hh[j] = (short)hb;
            ll[j] = (short)f2bf(f - bf2f(hb));
        }
        size_t base = (size_t)(kk >> 4) * 8192 + (size_t)(q * 16 + (kk & 15)) * 16;
        *(short8*)(blob + base + (kd * 2 + 0) * 1024) = hh;
        *(short8*)(blob + base + (kd * 2 + 1) * 1024) = ll;
    }
}

// ---------------------------------------------------------------------------
// MFMA argmax — exact round-9 structure (best measured: 177.8 us, MfmaUtil
// 53.5%, ~95% of the 16x16 MFMA issue ceiling at 2 waves/SIMD). Block =
// 512 thr / 8 waves = (4 rowsets x 2 codesets), 256 rows/block, grid 256.
// Barrier-free K-loop, blob L2-resident, global->VGPR ping-pong, med3
// second-best fold, setprio around the MFMA cluster.
// NOTE (r7/r10): raising min-waves caps VGPR far below the ~250-reg demand
// -> multi-GB spill. 2 waves/SIMD is the occupancy ceiling for this shape.
// Tail: LDS-transposed gather-write.
// ---------------------------------------------------------------------------
__global__ __launch_bounds__(512, 2)
void k_argmax(const float* __restrict__ x, const char* __restrict__ blob,
              const float* __restrict__ cbn, float* __restrict__ invn,
              float* __restrict__ out, float* __restrict__ lossacc,
              int* __restrict__ rcnt, int* __restrict__ rlist) {
    __shared__ __align__(16) char smem[33280];
    float* xt   = (float*)smem;              // [64][129] (preamble overlay)
    float* invl = (float*)(smem + 33024);    // [64]

    const int tid  = threadIdx.x;
    const int w    = tid >> 6;
    const int lane = tid & 63;
    const int m16  = lane & 15;
    const int quad = lane >> 4;
    const int rs   = w >> 1;      // rowset 0..3 (64 rows each)
    const int cs   = w & 1;       // codeset 0/1 (16 codes per tile)
    const int n0   = blockIdx.x * 256;
    const int bI   = n0 >> 12;
    const int l0   = n0 & (Lc - 1);
    const float* xb = x + (size_t)bI * Dc * Lc;

    // ---- preamble: 4 halves of 64 rows: transpose, normalize, build A frags
    short8 ah[4][4], al[4][4];
    for (int h = 0; h < 4; ++h) {
        __syncthreads();
        #pragma unroll
        for (int j = 0; j < 4; ++j) {
            int fl = tid + j * 512;              // 0..2047
            int d = fl >> 4, lq = fl & 15;
            float4 v = *(const float4*)(xb + (size_t)d * Lc + l0 + h * 64 + lq * 4);
            xt[(lq * 4 + 0) * 129 + d] = v.x;
            xt[(lq * 4 + 1) * 129 + d] = v.y;
            xt[(lq * 4 + 2) * 129 + d] = v.z;
            xt[(lq * 4 + 3) * 129 + d] = v.w;
        }
        __syncthreads();
        {   // row norms, 8 threads/row
            int row = tid >> 3, q = tid & 7;
            float s = 0.f;
            #pragma unroll
            for (int j = 0; j < 16; ++j) { float t = xt[row * 129 + q * 16 + j]; s += t * t; }
            s += __shfl_down(s, 1); s += __shfl_down(s, 2); s += __shfl_down(s, 4);
            if (q == 0) {
                float inv = 1.f / fmaxf(sqrtf(s), EPSF);
                invl[row] = inv;
                invn[n0 + h * 64 + row] = inv;
            }
        }
        __syncthreads();
        if (rs == h) {   // both cs-waves of this rowset build the frags
            #pragma unroll
            for (int rt = 0; rt < 4; ++rt) {
                int rl = rt * 16 + m16;          // A layout: m = lane&15
                float inv = invl[rl];
                #pragma unroll
                for (int kd = 0; kd < 4; ++kd) {
                    int dof = kd * 32 + quad * 8;   // k = quad*8 + j
                    short8 hhv, llv;
                    #pragma unroll
                    for (int j = 0; j < 8; ++j) {
                        float xn = xt[rl * 129 + dof + j] * inv;
                        unsigned short hb = f2bf(xn);
                        hhv[j] = (short)hb;
                        llv[j] = (short)f2bf(xn - bf2f(hb));
                    }
                    ah[rt][kd] = hhv; al[rt][kd] = llv;
                }
            }
        }
    }
    __syncthreads();

    // ---- K loop: 128 tiles of 32 codes (16 per codeset), barrier-free ----
    const f32x4 fz = {0.f, 0.f, 0.f, 0.f};
    float Bb[16], Ss[16];
    #pragma unroll
    for (int i = 0; i < 16; ++i) { Bb[i] = -3.0e38f; Ss[i] = -3.0e38f; }
    unsigned kc8 = (unsigned)cs;     // packed tag = code>>4 = t*2+cs

    const char* pb = blob + (size_t)cs * 8192 + (size_t)lane * 16;

    auto tileStep = [&](const short8* Bf) {
        f32x4 acc[4];
        __builtin_amdgcn_s_setprio(1);
        #pragma unroll
        for (int kd = 0; kd < 4; ++kd) {
            short8 bh = Bf[kd * 2];
            short8 bl = Bf[kd * 2 + 1];
            #pragma unroll
            for (int rt = 0; rt < 4; ++rt)
                acc[rt] = __builtin_amdgcn_mfma_f32_16x16x32_bf16(
                    ah[rt][kd], bh, (kd == 0) ? fz : acc[rt], 0, 0, 0);
            #pragma unroll
            for (int rt = 0; rt < 4; ++rt)
                acc[rt] = __builtin_amdgcn_mfma_f32_16x16x32_bf16(
                    ah[rt][kd], bl, acc[rt], 0, 0, 0);
            #pragma unroll
            for (int rt = 0; rt < 4; ++rt)
                acc[rt] = __builtin_amdgcn_mfma_f32_16x16x32_bf16(
                    al[rt][kd], bh, acc[rt], 0, 0, 0);
        }
        __builtin_amdgcn_s_setprio(0);
        // fold: Ss <= Bb invariant -> med3(Bb, p, Ss) is exact second-best.
        #pragma unroll
        for (int rt = 0; rt < 4; ++rt)
            #pragma unroll
            for (int rg = 0; rg < 4; ++rg) {
                int s = rt * 4 + rg;
                float p = __uint_as_float(
                    (__float_as_uint(acc[rt][rg]) & 0xFFFFFF00u) | kc8);
                Ss[s] = __builtin_amdgcn_fmed3f(Bb[s], p, Ss[s]);
                Bb[s] = fmaxf(Bb[s], p);
            }
        kc8 += 2;
    };

    short8 bA[8], bB[8];
    #pragma unroll
    for (int f = 0; f < 8; ++f) bA[f] = *(const short8*)(pb + f * 1024);

    for (int tt = 0; tt < 64; ++tt) {
        {   // even tile t = 2*tt: prefetch t+1 into bB, compute bA
            const int t = 2 * tt;
            const char* p = pb + (size_t)(t + 1) * 16384;
            #pragma unroll
            for (int f = 0; f < 8; ++f) bB[f] = *(const short8*)(p + f * 1024);
            tileStep(bA);
        }
        {   // odd tile t = 2*tt+1: prefetch t+1 into bA (clamp last), compute bB
            const int t = 2 * tt + 1;
            const size_t tn = (t < 127) ? (size_t)(t + 1) : (size_t)t;
            const char* p = pb + tn * 16384;
            #pragma unroll
            for (int f = 0; f < 8; ++f) bA[f] = *(const short8*)(p + f * 1024);
            tileStep(bB);
        }
    }

    // ---- epilogue: merge 16 m16-lanes per slot ----
    float mv1[16], mv2[16]; int mk1[16];
    #pragma unroll
    for (int s = 0; s < 16; ++s) {
        float v1 = Bb[s], v2 = Ss[s];
        int k1 = (int)(((__float_as_uint(v1) & 0xFFu) << 4) | (unsigned)m16);
        #pragma unroll
        for (int off = 1; off < 16; off <<= 1) {
            float ov1 = __shfl_xor(v1, off);
            float ov2 = __shfl_xor(v2, off);
            int   ok1 = __shfl_xor(k1, off);
            bool gt = ov1 > v1, eq = ov1 == v1;
            v2 = gt ? fmaxf(ov2, v1) : fmaxf(v2, ov1);
            v1 = gt ? ov1 : v1;
            k1 = gt ? ok1 : (eq ? min(k1, ok1) : k1);
        }
        mv1[s] = v1; mv2[s] = v2; mk1[s] = k1;
    }
    // cross-codeset merge via LDS: [256 rows][2 cs]
    float* Ev = (float*)smem;                // 2048 B
    float* Sv = (float*)(smem + 2048);
    int*   Kv = (int*)(smem + 4096);
    float* bsum = (float*)(smem + 6144);
    int*   sidx = (int*)(smem + 8192);       // [256] final code per row
    __syncthreads();
    if (tid == 0) *bsum = 0.f;
    if (m16 == 0) {
        #pragma unroll
        for (int s = 0; s < 16; ++s) {
            int rt = s >> 2, rg = s & 3;
            int row = rs * 64 + rt * 16 + quad * 4 + rg;   // C row = quad*4+reg
            Ev[row * 2 + cs] = mv1[s];
            Sv[row * 2 + cs] = mv2[s];
            Kv[row * 2 + cs] = mk1[s];
        }
    }
    __syncthreads();
    if (tid < 256) {
        float v1 = Ev[tid * 2], v2 = Sv[tid * 2];
        int   k1 = Kv[tid * 2];
        float ov1 = Ev[tid * 2 + 1], ov2 = Sv[tid * 2 + 1];
        int   ok1 = Kv[tid * 2 + 1];
        bool gt = ov1 > v1, eq = ov1 == v1;
        v2 = gt ? fmaxf(ov2, v1) : fmaxf(v2, ov1);
        v1 = gt ? ov1 : v1;
        k1 = gt ? ok1 : (eq ? min(k1, ok1) : k1);
        sidx[tid] = k1;
        atomicAdd(bsum, v1);
        if (v1 - v2 < TAU) {
            int pos = atomicAdd(rcnt, 1);
            if (pos < RCAP) rlist[pos] = n0 + tid;
        }
    }
    __syncthreads();
    if (tid == 0) atomicAdd(lossacc, *bsum);

    // ---- fused output write via LDS transpose: 4 chunks of 64 rows.
    int myk[4];
    #pragma unroll
    for (int c = 0; c < 4; ++c) myk[c] = sidx[c * 64 + (tid >> 3)];
    float* tb = (float*)smem;                // [64][130] = 33280 B
    float* ob = out + (size_t)bI * Dc * Lc + l0;
    #pragma unroll 1
    for (int c = 0; c < 4; ++c) {
        __syncthreads();                     // prior chunk reads / sidx done
        {
            const float4* src = (const float4*)(cbn + (size_t)myk[c] * Dc + (tid & 7) * 16);
            float4 v0 = src[0], v1 = src[1], v2 = src[2], v3 = src[3];
            float* dst = tb + (tid >> 3) * 130 + (tid & 7) * 16;
            *(float4*)(dst + 0)  = v0;
            *(float4*)(dst + 4)  = v1;
            *(float4*)(dst + 8)  = v2;
            *(float4*)(dst + 12) = v3;
        }
        __syncthreads();
        {
            int l = tid & 63, d0 = tid >> 6;     // wave = fixed d, l 0..63
            #pragma unroll
            for (int dd = 0; dd < 16; ++dd) {
                int d = d0 * 16 + dd;
                ob[(size_t)d * Lc + c * 64 + l] = tb[l * 130 + d];
            }
        }
    }
}

// ---------------------------------------------------------------------------
// Exact fp32 re-argmax for flagged queries, latency-optimized: 512 threads,
// 8 codes/thread as 4 code-pairs with two INDEPENDENT fmaf chains (load-ILP
// ~2x32 float4 in flight) + 8-wave TLP. Per-(query,code) dot uses the exact
// ascending-j single-chain fmaf order of the r9-passing kernel; codes
// ascending per thread; packed-key max-v1/min-k reduction -> result
// identical to the old repair (only thread<->code partition changed).
// Rewrites the out row; last block (done counter) writes the scalar loss.
// ---------------------------------------------------------------------------
__global__ __launch_bounds__(512)
void k_repair(const float* __restrict__ x, const float* __restrict__ invn,
              const float* __restrict__ cbn, float* __restrict__ out,
              const int* __restrict__ rcnt, const int* __restrict__ rlist,
              const float* __restrict__ lacc, int* __restrict__ done) {
    __shared__ float xs[128];
    __shared__ unsigned long long red[8];
    __shared__ int fk;
    int cnt = *rcnt; if (cnt > RCAP) cnt = RCAP;
    const int tid = threadIdx.x;
    for (int e = blockIdx.x; e < cnt; e += gridDim.x) {
        int n = rlist[e]; int b = n >> 12; int l = n & (Lc - 1);
        __syncthreads();
        if (tid < 128)
            xs[tid] = x[(size_t)b * Dc * Lc + (size_t)tid * Lc + l] * invn[n];
        __syncthreads();
        const float4* xv = (const float4*)xs;
        float best = -3.0e38f; int bk = 0;
        #pragma unroll 1
        for (int ii = 0; ii < 4; ++ii) {
            int kA = (2 * ii + 0) * 512 + tid;    // ascending within thread
            int kB = (2 * ii + 1) * 512 + tid;
            const float4* ca = (const float4*)(cbn + (size_t)kA * Dc);
            const float4* cb = (const float4*)(cbn + (size_t)kB * Dc);
            float sA = 0.f, sB = 0.f;
            #pragma unroll
            for (int j = 0; j < 32; ++j) {
                float4 c = ca[j], d = cb[j], xx = xv[j];
                sA = fmaf(c.x, xx.x, sA); sA = fmaf(c.y, xx.y, sA);
                sA = fmaf(c.z, xx.z, sA); sA = fmaf(c.w, xx.w, sA);
                sB = fmaf(d.x, xx.x, sB); sB = fmaf(d.y, xx.y, sB);
                sB = fmaf(d.z, xx.z, sB); sB = fmaf(d.w, xx.w, sB);
            }
            if (sA > best) { best = sA; bk = kA; }
            if (sB > best) { best = sB; bk = kB; }
        }
        unsigned kb = __float_as_uint(best);
        kb = (kb & 0x80000000u) ? ~kb : (kb | 0x80000000u);
        unsigned long long pk =
            ((unsigned long long)kb << 32) | (unsigned)(0xFFFFFFFFu - (unsigned)bk);
        #pragma unroll
        for (int off = 32; off >= 1; off >>= 1) {
            unsigned long long o = __shfl_xor(pk, off);
            pk = (o > pk) ? o : pk;
        }
        if ((tid & 63) == 0) red[tid >> 6] = pk;
        __syncthreads();
        if (tid == 0) {
            unsigned long long m = red[0];
            #pragma unroll
            for (int i = 1; i < 8; ++i) if (red[i] > m) m = red[i];
            fk = (int)(0xFFFFFFFFu - (unsigned)(m & 0xFFFFFFFFull));
        }
        __syncthreads();
        if (tid < 128)       // rewrite output row with exact code
            out[(size_t)b * Dc * Lc + (size_t)tid * Lc + l] = cbn[(size_t)fk * Dc + tid];
    }
    // ---- fused loss finalize: last block writes the scalar
    __syncthreads();
    if (tid == 0) {
        int old = atomicAdd(done, 1);
        if (old == (int)gridDim.x - 1)
            out[(size_t)Bc * Dc * Lc] = 2.0f - 2.0f * (*lacc) / (float)Nc;
    }
}

// ---------------------------------------------------------------------------
extern "C" void kernel_launch(void* const* d_in, const int* in_sizes, int n_in,
                              void* d_out, int out_size, void* d_ws, size_t ws_size,
                              hipStream_t stream) {
    const float* x   = (const float*)d_in[0];   // [16][128][4096] fp32
    const float* emb = (const float*)d_in[1];   // [4096][128] fp32
    float* out = (float*)d_out;

    char* ws = (char*)d_ws;
    float* cbn  = (float*)ws;                                  // 2 MB
    char*  blob = ws + (2u << 20);                             // 2 MB
    float* invn = (float*)(ws + (4u << 20));                   // 256 KB
    char*  b5   = ws + (4u << 20) + (512u << 10);
    float* lacc = (float*)b5;
    int*   rcnt = (int*)(b5 + 64);
    int*   done = (int*)(b5 + 128);
    int*   rlist= (int*)(b5 + 1024);                           // 128 KB

    k_prep  <<<Kc / 4,   256, 0, stream>>>(emb, cbn, blob, lacc, rcnt, done);
    k_argmax<<<Nc / 256, 512, 0, stream>>>(x, blob, cbn, invn, out, lacc, rcnt, rlist);
    k_repair<<<2048,     512, 0, stream>>>(x, invn, cbn, out, rcnt, rlist, lacc, done);
}

// Round 14
// 323.423 us; speedup vs baseline: 5.2320x; 1.2118x over previous
//
#include <hip/hip_runtime.h>
#include <cstddef>

#define EPSF 1e-12f

constexpr int Bc = 16, Dc = 128, Lc = 4096, Kc = 4096;
constexpr int Nc = Bc * Lc;     // 65536
constexpr float TAU = 1e-4f;    // 2x split-bf16 err (~4e-5) + 8-bit pack err (~6e-5)
constexpr int RCAP = 32768;

typedef __attribute__((ext_vector_type(8))) short short8;
typedef __attribute__((ext_vector_type(4))) float f32x4;

__device__ __forceinline__ unsigned short f2bf(float f) {
    unsigned u = __float_as_uint(f);
    return (unsigned short)((u + 0x7fffu + ((u >> 16) & 1u)) >> 16);
}
__device__ __forceinline__ float bf2f(unsigned short u) {
    return __uint_as_float(((unsigned)u) << 16);
}

// ---------------------------------------------------------------------------
// Fused codebook prep: normalize -> cbn (f32) AND pack MFMA-operand blob.
// Blob layout: group g (16 codes) -> 8 frags (kd 0..3 x {hi,lo}) of 1024B;
// within a frag, 16B slot l = q*16 + (k&15) holds bf16 of dims (kd*4+q)*8..+7
// of code k. Zero-inits loss / repair counter / done (graph-replay safe).
// ---------------------------------------------------------------------------
__global__ void k_prep(const float* __restrict__ emb, float* __restrict__ cbn,
                       char* __restrict__ blob, float* __restrict__ lacc,
                       int* __restrict__ rcnt, int* __restrict__ done) {
    __shared__ float cls[4][128];
    const int tid  = threadIdx.x;
    const int w    = tid >> 6;
    const int lane = tid & 63;
    const int k    = (blockIdx.x << 2) + w;

    float2 v = ((const float2*)(emb + (size_t)k * Dc))[lane];
    float s = v.x * v.x + v.y * v.y;
    #pragma unroll
    for (int off = 32; off > 0; off >>= 1) s += __shfl_down(s, off);
    s = __shfl(s, 0);
    float inv = 1.f / fmaxf(sqrtf(s), EPSF);
    v.x *= inv; v.y *= inv;
    ((float2*)(cbn + (size_t)k * Dc))[lane] = v;
    cls[w][lane * 2]     = v.x;
    cls[w][lane * 2 + 1] = v.y;
    if (blockIdx.x == 0 && tid == 0) { *lacc = 0.f; *rcnt = 0; *done = 0; }
    __syncthreads();

    if (tid < 64) {           // 4 codes x 16 chunks
        int kl = tid >> 4, c = tid & 15;
        int kk = (blockIdx.x << 2) + kl;
        int kd = c >> 2, q = c & 3;
        short8 hh, ll;
        #pragma unroll
        for (int j = 0; j < 8; ++j) {
            float f = cls[kl][c * 8 + j];
            unsigned short hb = f2bf(f);
            hh[j] = (short)hb;
            ll[j] = (short)f2bf(f - bf2f(hb));
        }
        size_t base = (size_t)(kk >> 4) * 8192 + (size_t)(q * 16 + (kk & 15)) * 16;
        *(short8*)(blob + base + (kd * 2 + 0) * 1024) = hh;
        *(short8*)(blob + base + (kd * 2 + 1) * 1024) = ll;
    }
}

// ---------------------------------------------------------------------------
// MFMA argmax — exact round-9 structure (best measured: 177.8 us, MfmaUtil
// 53.5%, ~95% of the 16x16 MFMA issue ceiling at 2 waves/SIMD). Block =
// 512 thr / 8 waves = (4 rowsets x 2 codesets), 256 rows/block, grid 256.
// Barrier-free K-loop, blob L2-resident, global->VGPR ping-pong, med3
// second-best fold, setprio around the MFMA cluster.
// NOTE (r7/r10): raising min-waves caps VGPR far below the ~250-reg demand
// -> multi-GB spill. 2 waves/SIMD is the occupancy ceiling for this shape.
// Tail: LDS-transposed gather-write.
// ---------------------------------------------------------------------------
__global__ __launch_bounds__(512, 2)
void k_argmax(const float* __restrict__ x, const char* __restrict__ blob,
              const float* __restrict__ cbn, float* __restrict__ invn,
              float* __restrict__ out, float* __restrict__ lossacc,
              int* __restrict__ rcnt, int* __restrict__ rlist) {
    __shared__ __align__(16) char smem[33280];
    float* xt   = (float*)smem;              // [64][129] (preamble overlay)
    float* invl = (float*)(smem + 33024);    // [64]

    const int tid  = threadIdx.x;
    const int w    = tid >> 6;
    const int lane = tid & 63;
    const int m16  = lane & 15;
    const int quad = lane >> 4;
    const int rs   = w >> 1;      // rowset 0..3 (64 rows each)
    const int cs   = w & 1;       // codeset 0/1 (16 codes per tile)
    const int n0   = blockIdx.x * 256;
    const int bI   = n0 >> 12;
    const int l0   = n0 & (Lc - 1);
    const float* xb = x + (size_t)bI * Dc * Lc;

    // ---- preamble: 4 halves of 64 rows: transpose, normalize, build A frags
    short8 ah[4][4], al[4][4];
    for (int h = 0; h < 4; ++h) {
        __syncthreads();
        #pragma unroll
        for (int j = 0; j < 4; ++j) {
            int fl = tid + j * 512;              // 0..2047
            int d = fl >> 4, lq = fl & 15;
            float4 v = *(const float4*)(xb + (size_t)d * Lc + l0 + h * 64 + lq * 4);
            xt[(lq * 4 + 0) * 129 + d] = v.x;
            xt[(lq * 4 + 1) * 129 + d] = v.y;
            xt[(lq * 4 + 2) * 129 + d] = v.z;
            xt[(lq * 4 + 3) * 129 + d] = v.w;
        }
        __syncthreads();
        {   // row norms, 8 threads/row
            int row = tid >> 3, q = tid & 7;
            float s = 0.f;
            #pragma unroll
            for (int j = 0; j < 16; ++j) { float t = xt[row * 129 + q * 16 + j]; s += t * t; }
            s += __shfl_down(s, 1); s += __shfl_down(s, 2); s += __shfl_down(s, 4);
            if (q == 0) {
                float inv = 1.f / fmaxf(sqrtf(s), EPSF);
                invl[row] = inv;
                invn[n0 + h * 64 + row] = inv;
            }
        }
        __syncthreads();
        if (rs == h) {   // both cs-waves of this rowset build the frags
            #pragma unroll
            for (int rt = 0; rt < 4; ++rt) {
                int rl = rt * 16 + m16;          // A layout: m = lane&15
                float inv = invl[rl];
                #pragma unroll
                for (int kd = 0; kd < 4; ++kd) {
                    int dof = kd * 32 + quad * 8;   // k = quad*8 + j
                    short8 hhv, llv;
                    #pragma unroll
                    for (int j = 0; j < 8; ++j) {
                        float xn = xt[rl * 129 + dof + j] * inv;
                        unsigned short hb = f2bf(xn);
                        hhv[j] = (short)hb;
                        llv[j] = (short)f2bf(xn - bf2f(hb));
                    }
                    ah[rt][kd] = hhv; al[rt][kd] = llv;
                }
            }
        }
    }
    __syncthreads();

    // ---- K loop: 128 tiles of 32 codes (16 per codeset), barrier-free ----
    const f32x4 fz = {0.f, 0.f, 0.f, 0.f};
    float Bb[16], Ss[16];
    #pragma unroll
    for (int i = 0; i < 16; ++i) { Bb[i] = -3.0e38f; Ss[i] = -3.0e38f; }
    unsigned kc8 = (unsigned)cs;     // packed tag = code>>4 = t*2+cs

    const char* pb = blob + (size_t)cs * 8192 + (size_t)lane * 16;

    auto tileStep = [&](const short8* Bf) {
        f32x4 acc[4];
        __builtin_amdgcn_s_setprio(1);
        #pragma unroll
        for (int kd = 0; kd < 4; ++kd) {
            short8 bh = Bf[kd * 2];
            short8 bl = Bf[kd * 2 + 1];
            #pragma unroll
            for (int rt = 0; rt < 4; ++rt)
                acc[rt] = __builtin_amdgcn_mfma_f32_16x16x32_bf16(
                    ah[rt][kd], bh, (kd == 0) ? fz : acc[rt], 0, 0, 0);
            #pragma unroll
            for (int rt = 0; rt < 4; ++rt)
                acc[rt] = __builtin_amdgcn_mfma_f32_16x16x32_bf16(
                    ah[rt][kd], bl, acc[rt], 0, 0, 0);
            #pragma unroll
            for (int rt = 0; rt < 4; ++rt)
                acc[rt] = __builtin_amdgcn_mfma_f32_16x16x32_bf16(
                    al[rt][kd], bh, acc[rt], 0, 0, 0);
        }
        __builtin_amdgcn_s_setprio(0);
        // fold: Ss <= Bb invariant -> med3(Bb, p, Ss) is exact second-best.
        #pragma unroll
        for (int rt = 0; rt < 4; ++rt)
            #pragma unroll
            for (int rg = 0; rg < 4; ++rg) {
                int s = rt * 4 + rg;
                float p = __uint_as_float(
                    (__float_as_uint(acc[rt][rg]) & 0xFFFFFF00u) | kc8);
                Ss[s] = __builtin_amdgcn_fmed3f(Bb[s], p, Ss[s]);
                Bb[s] = fmaxf(Bb[s], p);
            }
        kc8 += 2;
    };

    short8 bA[8], bB[8];
    #pragma unroll
    for (int f = 0; f < 8; ++f) bA[f] = *(const short8*)(pb + f * 1024);

    for (int tt = 0; tt < 64; ++tt) {
        {   // even tile t = 2*tt: prefetch t+1 into bB, compute bA
            const int t = 2 * tt;
            const char* p = pb + (size_t)(t + 1) * 16384;
            #pragma unroll
            for (int f = 0; f < 8; ++f) bB[f] = *(const short8*)(p + f * 1024);
            tileStep(bA);
        }
        {   // odd tile t = 2*tt+1: prefetch t+1 into bA (clamp last), compute bB
            const int t = 2 * tt + 1;
            const size_t tn = (t < 127) ? (size_t)(t + 1) : (size_t)t;
            const char* p = pb + tn * 16384;
            #pragma unroll
            for (int f = 0; f < 8; ++f) bA[f] = *(const short8*)(p + f * 1024);
            tileStep(bB);
        }
    }

    // ---- epilogue: merge 16 m16-lanes per slot ----
    float mv1[16], mv2[16]; int mk1[16];
    #pragma unroll
    for (int s = 0; s < 16; ++s) {
        float v1 = Bb[s], v2 = Ss[s];
        int k1 = (int)(((__float_as_uint(v1) & 0xFFu) << 4) | (unsigned)m16);
        #pragma unroll
        for (int off = 1; off < 16; off <<= 1) {
            float ov1 = __shfl_xor(v1, off);
            float ov2 = __shfl_xor(v2, off);
            int   ok1 = __shfl_xor(k1, off);
            bool gt = ov1 > v1, eq = ov1 == v1;
            v2 = gt ? fmaxf(ov2, v1) : fmaxf(v2, ov1);
            v1 = gt ? ov1 : v1;
            k1 = gt ? ok1 : (eq ? min(k1, ok1) : k1);
        }
        mv1[s] = v1; mv2[s] = v2; mk1[s] = k1;
    }
    // cross-codeset merge via LDS: [256 rows][2 cs]
    float* Ev = (float*)smem;                // 2048 B
    float* Sv = (float*)(smem + 2048);
    int*   Kv = (int*)(smem + 4096);
    float* bsum = (float*)(smem + 6144);
    int*   sidx = (int*)(smem + 8192);       // [256] final code per row
    __syncthreads();
    if (tid == 0) *bsum = 0.f;
    if (m16 == 0) {
        #pragma unroll
        for (int s = 0; s < 16; ++s) {
            int rt = s >> 2, rg = s & 3;
            int row = rs * 64 + rt * 16 + quad * 4 + rg;   // C row = quad*4+reg
            Ev[row * 2 + cs] = mv1[s];
            Sv[row * 2 + cs] = mv2[s];
            Kv[row * 2 + cs] = mk1[s];
        }
    }
    __syncthreads();
    if (tid < 256) {
        float v1 = Ev[tid * 2], v2 = Sv[tid * 2];
        int   k1 = Kv[tid * 2];
        float ov1 = Ev[tid * 2 + 1], ov2 = Sv[tid * 2 + 1];
        int   ok1 = Kv[tid * 2 + 1];
        bool gt = ov1 > v1, eq = ov1 == v1;
        v2 = gt ? fmaxf(ov2, v1) : fmaxf(v2, ov1);
        v1 = gt ? ov1 : v1;
        k1 = gt ? ok1 : (eq ? min(k1, ok1) : k1);
        sidx[tid] = k1;
        atomicAdd(bsum, v1);
        if (v1 - v2 < TAU) {
            int pos = atomicAdd(rcnt, 1);
            if (pos < RCAP) rlist[pos] = n0 + tid;
        }
    }
    __syncthreads();
    if (tid == 0) atomicAdd(lossacc, *bsum);

    // ---- fused output write via LDS transpose: 4 chunks of 64 rows.
    int myk[4];
    #pragma unroll
    for (int c = 0; c < 4; ++c) myk[c] = sidx[c * 64 + (tid >> 3)];
    float* tb = (float*)smem;                // [64][130] = 33280 B
    float* ob = out + (size_t)bI * Dc * Lc + l0;
    #pragma unroll 1
    for (int c = 0; c < 4; ++c) {
        __syncthreads();                     // prior chunk reads / sidx done
        {
            const float4* src = (const float4*)(cbn + (size_t)myk[c] * Dc + (tid & 7) * 16);
            float4 v0 = src[0], v1 = src[1], v2 = src[2], v3 = src[3];
            float* dst = tb + (tid >> 3) * 130 + (tid & 7) * 16;
            *(float4*)(dst + 0)  = v0;
            *(float4*)(dst + 4)  = v1;
            *(float4*)(dst + 8)  = v2;
            *(float4*)(dst + 12) = v3;
        }
        __syncthreads();
        {
            int l = tid & 63, d0 = tid >> 6;     // wave = fixed d, l 0..63
            #pragma unroll
            for (int dd = 0; dd < 16; ++dd) {
                int d = d0 * 16 + dd;
                ob[(size_t)d * Lc + c * 64 + l] = tb[l * 130 + d];
            }
        }
    }
}

// ---------------------------------------------------------------------------
// Exact fp32 re-argmax, COALESCED: wave-per-code-pair. Lanes 0-31 hold code
// k's 128 floats (float4/lane), lanes 32-63 code k+1 -> every code load is
// one coalesced 1KB wave transaction (vs 64 scattered lines in all prior
// variants: the r5-r13 repairs were request-rate bound, ~140-370 us at
// VALUBusy ~1.5%). Dot = 4-dim lane chain + 5-step shfl_xor tree per half;
// per-half running (best,bk); final packed-key (v1|~k) max-reduce across
// lanes + waves -> exact max-v1 / min-k, partition-order independent.
// Rewrites out row; last block (done counter) writes the scalar loss.
// ---------------------------------------------------------------------------
__global__ __launch_bounds__(512)
void k_repair(const float* __restrict__ x, const float* __restrict__ invn,
              const float* __restrict__ cbn, float* __restrict__ out,
              const int* __restrict__ rcnt, const int* __restrict__ rlist,
              const float* __restrict__ lacc, int* __restrict__ done) {
    __shared__ __align__(16) float xs[128];
    __shared__ unsigned long long red[8];
    __shared__ int fk;
    int cnt = *rcnt; if (cnt > RCAP) cnt = RCAP;
    const int tid  = threadIdx.x;
    const int w    = tid >> 6;
    const int lane = tid & 63;
    const int half = lane >> 5;        // 0: even code, 1: odd code
    const int l32  = lane & 31;
    for (int e = blockIdx.x; e < cnt; e += gridDim.x) {
        int n = rlist[e]; int b = n >> 12; int l = n & (Lc - 1);
        __syncthreads();
        if (tid < 128)
            xs[tid] = x[(size_t)b * Dc * Lc + (size_t)tid * Lc + l] * invn[n];
        __syncthreads();
        const float4 xv = ((const float4*)xs)[l32];   // lane's 4 dims (fixed)
        float best = -3.0e38f; int bk = 0;
        // wave w owns codes [w*512, w*512+512); pair (k, k+1) per iteration
        #pragma unroll 4
        for (int i = 0; i < 256; ++i) {
            int k = w * 512 + i * 2 + half;
            float4 cv = ((const float4*)(cbn + (size_t)k * Dc))[l32];
            float s = cv.x * xv.x;
            s = fmaf(cv.y, xv.y, s);
            s = fmaf(cv.z, xv.z, s);
            s = fmaf(cv.w, xv.w, s);
            #pragma unroll
            for (int off = 1; off < 32; off <<= 1)
                s += __shfl_xor(s, off);     // tree sum within each half-wave
            if (s > best) { best = s; bk = k; }   // ascending k per half
        }
        // packed key: max v1, tie -> min k (order-independent)
        unsigned kb = __float_as_uint(best);
        kb = (kb & 0x80000000u) ? ~kb : (kb | 0x80000000u);
        unsigned long long pk =
            ((unsigned long long)kb << 32) | (unsigned)(0xFFFFFFFFu - (unsigned)bk);
        #pragma unroll
        for (int off = 1; off < 64; off <<= 1) {
            unsigned long long o = __shfl_xor(pk, off);
            pk = (o > pk) ? o : pk;
        }
        if (lane == 0) red[w] = pk;
        __syncthreads();
        if (tid == 0) {
            unsigned long long m = red[0];
            #pragma unroll
            for (int i = 1; i < 8; ++i) if (red[i] > m) m = red[i];
            fk = (int)(0xFFFFFFFFu - (unsigned)(m & 0xFFFFFFFFull));
        }
        __syncthreads();
        if (tid < 128)       // rewrite output row with exact code
            out[(size_t)b * Dc * Lc + (size_t)tid * Lc + l] = cbn[(size_t)fk * Dc + tid];
    }
    // ---- fused loss finalize: last block writes the scalar
    __syncthreads();
    if (tid == 0) {
        int old = atomicAdd(done, 1);
        if (old == (int)gridDim.x - 1)
            out[(size_t)Bc * Dc * Lc] = 2.0f - 2.0f * (*lacc) / (float)Nc;
    }
}

// ---------------------------------------------------------------------------
extern "C" void kernel_launch(void* const* d_in, const int* in_sizes, int n_in,
                              void* d_out, int out_size, void* d_ws, size_t ws_size,
                              hipStream_t stream) {
    const float* x   = (const float*)d_in[0];   // [16][128][4096] fp32
    const float* emb = (const float*)d_in[1];   // [4096][128] fp32
    float* out = (float*)d_out;

    char* ws = (char*)d_ws;
    float* cbn  = (float*)ws;                                  // 2 MB
    char*  blob = ws + (2u << 20);                             // 2 MB
    float* invn = (float*)(ws + (4u << 20));                   // 256 KB
    char*  b5   = ws + (4u << 20) + (512u << 10);
    float* lacc = (float*)b5;
    int*   rcnt = (int*)(b5 + 64);
    int*   done = (int*)(b5 + 128);
    int*   rlist= (int*)(b5 + 1024);                           // 128 KB

    k_prep  <<<Kc / 4,   256, 0, stream>>>(emb, cbn, blob, lacc, rcnt, done);
    k_argmax<<<Nc / 256, 512, 0, stream>>>(x, blob, cbn, invn, out, lacc, rcnt, rlist);
    k_repair<<<2048,     512, 0, stream>>>(x, invn, cbn, out, rcnt, rlist, lacc, done);
}